// Round 7
// baseline (572.665 us; speedup 1.0000x reference)
//
#include <hip/hip_runtime.h>
#include <hip/hip_bf16.h>

// ---------------------------------------------------------------------------
// PCELayer R7.
//  conv_mfma = R5's proven 16x16x32 version (167 us) + W register prefetch
//    issued AFTER the publish barrier (so the compiler's vmcnt(0)-at-barrier
//    drain happens BEFORE issue; loads land during the tap's MFMA window).
//    R6's mistakes reverted: no 32x32 (reg spill -> +142MB scratch traffic),
//    no global_load_lds staging, no prefetch-before-barrier.
//  norm2 fused into pw2's B-tile staging (h2 read exactly once by pw2);
//    norm2_kernel deleted (saves 33.5 MB RT + a launch).
// Workspace (153.6 MB):
//   head 16K: wts/stats1/stats2/stats3/statsE
//   wp1T 128K | wp2T 128K
//   XT 16.8M (-> combined_cl after conv) | WT 2.4M
//   YS 134.2M (-> h1cl 67M | h2cl 16.8M | h3 8.4M after combine)
// ---------------------------------------------------------------------------

#define B_ 16
#define CIN_ 128
#define COUT_ 128
#define H_ 64
#define W_ 64
#define HW_ 4096
#define E_ 8
#define FF_ 8
#define GC_ 32
#define HID_ 64
#define HC_ 512

typedef __hip_bfloat16 bf16;
typedef __bf16 bf16x8 __attribute__((ext_vector_type(8)));
typedef float f32x4 __attribute__((ext_vector_type(4)));

__device__ __forceinline__ float siluf(float v) { return v / (1.f + __expf(-v)); }
__device__ __forceinline__ float bf2f(bf16 v) { return __bfloat162float(v); }
__device__ __forceinline__ bf16 f2bf(float v) { return __float2bfloat16(v); }

// ---------------- router gate ----------------------------------------------
__global__ void gate_kernel(const float* __restrict__ w1, const float* __restrict__ b1,
                            const float* __restrict__ w2, const float* __restrict__ b2,
                            float* __restrict__ wts) {
  int p = threadIdx.x;
  if (p >= 16) return;
  int i = p >> 2, j = p & 3;
  float cy = (i + 0.5f) * 0.25f;
  float cx = (j + 0.5f) * 0.25f;
  float feats[GC_];
#pragma unroll
  for (int f = 0; f < FF_; ++f) {
    float fr = 3.14159265358979f * (float)(1 << f);
    float ay = cy * fr, ax = cx * fr;
    feats[f] = sinf(ay);
    feats[FF_ + f] = cosf(ay);
    feats[2 * FF_ + f] = sinf(ax);
    feats[3 * FF_ + f] = cosf(ax);
  }
  float hid[HID_];
  for (int k = 0; k < HID_; ++k) {
    float a = b1[k];
#pragma unroll
    for (int m = 0; m < GC_; ++m) a = fmaf(feats[m], w1[m * HID_ + k], a);
    hid[k] = siluf(a);
  }
  float lg[E_];
  float mx = -1e30f;
#pragma unroll
  for (int e = 0; e < E_; ++e) {
    float a = b2[e];
    for (int k = 0; k < HID_; ++k) a = fmaf(hid[k], w2[k * E_ + e], a);
    lg[e] = a;
    mx = fmaxf(mx, a);
  }
  float s = 0.f;
#pragma unroll
  for (int e = 0; e < E_; ++e) { lg[e] = __expf(lg[e] - mx); s += lg[e]; }
  float inv = 1.f / s;
#pragma unroll
  for (int e = 0; e < E_; ++e) wts[p * E_ + e] = lg[e] * inv;
}

// ---------------- x -> channels-last bf16 ----------------------------------
__global__ __launch_bounds__(256) void xt_kernel(const float* __restrict__ x,
                                                 bf16* __restrict__ xT) {
  __shared__ float t[128][65];
  int b = blockIdx.x >> 6, h = blockIdx.x & 63;
  int tid = threadIdx.x;
  int w = tid & 63, c4 = tid >> 6;
  const float* xb = x + ((size_t)(b * 128) * 64 + h) * 64;
#pragma unroll 4
  for (int rep = 0; rep < 32; ++rep) {
    int ci = rep * 4 + c4;
    t[ci][w] = xb[(size_t)ci * HW_ + w];
  }
  __syncthreads();
  bf16* dst = xT + (size_t)(b * 64 + h) * 8192;
#pragma unroll 4
  for (int rep = 0; rep < 32; ++rep) {
    int o = rep * 256 + tid;
    int cg = o >> 9, w2 = (o >> 3) & 63, lo = o & 7;
    dst[o] = f2bf(t[cg * 8 + lo][w2]);
  }
}

// ---------------- w_exp -> wT bf16 -----------------------------------------
__global__ void wt_kernel(const float* __restrict__ w_exp, bf16* __restrict__ wT) {
  int idx = blockIdx.x * 256 + threadIdx.x;
  if (idx >= 1179648) return;
  int lo = idx & 7;
  int co = (idx >> 3) & 127;
  int cg = (idx >> 10) & 15;
  int rest = idx >> 14;
  int tap = rest % 9, e = rest / 9;
  int ci = cg * 8 + lo;
  wT[idx] = f2bf(w_exp[(((size_t)(e * 128 + co) * 128 + ci) * 9) + tap]);
}

// ---------------- pw weights fp32 -> bf16 ----------------------------------
__global__ void wpT_kernel(const float* __restrict__ w_pw1, const float* __restrict__ w_pw2,
                           bf16* __restrict__ wp1T, bf16* __restrict__ wp2T) {
  int idx = blockIdx.x * 256 + threadIdx.x;
  if (idx < 65536) wp1T[idx] = f2bf(w_pw1[idx]);
  else if (idx < 131072) wp2T[idx - 65536] = f2bf(w_pw2[idx - 65536]);
}

// ---------------- expert conv via MFMA (R5 structure + late W prefetch) ----
// grid: e(8) x b(16) x rt(16 tiles of 4 rows). 256 thr = 4 waves.
// Block: 128co x 256pos. Wave: row h_local=wave, 8mt x 4nt of 16x16.
__global__ __launch_bounds__(256, 2) void conv_mfma(
    const bf16* __restrict__ xT, const bf16* __restrict__ wT,
    float* __restrict__ statsE, bf16* __restrict__ ys) {
  __shared__ __align__(16) char xls[8 * 6144];   // [cg(8)][r(6)][w(64)]x16B = 48K
  __shared__ __align__(16) char wls[8 * 2048];   // [cg(8)][co(128)]x16B = 16K
  __shared__ float red[4][8][2];

  int blk = blockIdx.x;
  int rt = blk & 15, b = (blk >> 4) & 15, e = blk >> 8;
  int tid = threadIdx.x, lane = tid & 63, wave = tid >> 6;
  int quad = lane >> 4, l15 = lane & 15;
  int h0 = rt * 4;
  int h_local = wave;

  f32x4 acc[8][4];
#pragma unroll
  for (int mt = 0; mt < 8; ++mt)
#pragma unroll
    for (int nt = 0; nt < 4; ++nt) acc[mt][nt] = (f32x4){0.f, 0.f, 0.f, 0.f};

  bf16x8 bz;
#pragma unroll
  for (int j = 0; j < 8; ++j) bz[j] = (__bf16)0.f;

  // W prefetch regs: next (half,tap)'s 4 segments for this wave.
  uint4 wr[4];
  auto wload = [&](int ht2) {
    int hf = ht2 / 9, tp = ht2 - hf * 9;
#pragma unroll
    for (int s = 0; s < 4; ++s) {
      int seg = wave * 4 + s;
      int cg = seg >> 1, cb = seg & 1;
      wr[s] = *((const uint4*)((const char*)wT +
          ((size_t)(((e * 9 + tp) * 16) + hf * 8 + cg) * 128 + cb * 64) * 16) + lane);
    }
  };
  wload(0);

  for (int half = 0; half < 2; ++half) {
    __syncthreads();  // prior-half xls readers done
    // stage X: 48 segs (cg 8 x r 6) of 1KB, 12 per wave (vector loads)
#pragma unroll
    for (int s = 0; s < 12; ++s) {
      int seg = wave * 12 + s;
      int cg = seg / 6, r = seg % 6;
      int h = h0 - 1 + r;
      char* ldst = xls + cg * 6144 + r * 1024 + lane * 16;
      if ((unsigned)h < 64u) {
        const uint4* g = (const uint4*)((const char*)xT +
            ((size_t)((b * 64 + h) * 16) + half * 8 + cg) * 1024) + lane;
        *(uint4*)ldst = *g;
      } else {
        *(uint4*)ldst = make_uint4(0u, 0u, 0u, 0u);
      }
    }
    for (int tap = 0; tap < 9; ++tap) {
      int dr = tap / 3, ds = tap % 3;
      __syncthreads();  // A: prior tap's wls readers done
      // publish prefetched W regs (ds_write only; global already landed)
#pragma unroll
      for (int s = 0; s < 4; ++s) {
        int seg = wave * 4 + s;
        int cg = seg >> 1, cb = seg & 1;
        *(uint4*)(wls + cg * 2048 + cb * 1024 + lane * 16) = wr[s];
      }
      __syncthreads();  // B: wls (+ X on first tap) visible. vmcnt drained here.
      // Issue next tap's W loads NOW: they fly during this tap's MFMA and the
      // next barrier's vmcnt(0) drain is then free (R6 issued before barrier B
      // -> drained immediately -> no hiding).
      int ht2 = half * 9 + tap + 1;
      if (ht2 < 18) wload(ht2);
      int r_local = h_local + dr;
#pragma unroll
      for (int kc = 0; kc < 2; ++kc) {
        int cgq = kc * 4 + quad;
        bf16x8 af[8];
#pragma unroll
        for (int mt = 0; mt < 8; ++mt)
          af[mt] = *(const bf16x8*)(wls + cgq * 2048 + (mt * 16 + l15) * 16);
        bf16x8 bfr[4];
#pragma unroll
        for (int nt = 0; nt < 4; ++nt) {
          int w = nt * 16 + l15;
          int wsrc = w + ds - 1;
          bool valid = (unsigned)wsrc < 64u;
          int wc = valid ? wsrc : 0;
          bf16x8 v = *(const bf16x8*)(xls + cgq * 6144 + (r_local * 64 + wc) * 16);
          bfr[nt] = valid ? v : bz;
        }
#pragma unroll
        for (int mt = 0; mt < 8; ++mt)
#pragma unroll
          for (int nt = 0; nt < 4; ++nt)
            acc[mt][nt] = __builtin_amdgcn_mfma_f32_16x16x32_bf16(
                af[mt], bfr[nt], acc[mt][nt], 0, 0, 0);
      }
    }
  }

  // epilogue: raw ys + GN partial stats (group g = mt since co>>4 = mt)
  int hh = h0 + h_local;
  bf16* yb = ys + (size_t)((e * 16 + b) * 128) * 4096;
#pragma unroll
  for (int mt = 0; mt < 8; ++mt) {
    float s = 0.f, ss = 0.f;
#pragma unroll
    for (int nt = 0; nt < 4; ++nt) {
      int w = nt * 16 + l15;
      int pos = hh * 64 + w;
#pragma unroll
      for (int r = 0; r < 4; ++r) {
        float v = acc[mt][nt][r];
        s += v;
        ss += v * v;
        int co = mt * 16 + quad * 4 + r;
        yb[(size_t)co * 4096 + pos] = f2bf(v);
      }
    }
#pragma unroll
    for (int off = 32; off; off >>= 1) {
      s += __shfl_down(s, off, 64);
      ss += __shfl_down(ss, off, 64);
    }
    if (lane == 0) { red[wave][mt][0] = s; red[wave][mt][1] = ss; }
  }
  __syncthreads();
  if (tid < 16) {
    int g = tid >> 1, which = tid & 1;
    float t = red[0][g][which] + red[1][g][which] + red[2][g][which] + red[3][g][which];
    atomicAdd(&statsE[((e * 16 + b) * 8 + g) * 2 + which], t);
  }
}

// ---------------- generic stats finalize: raw S/SS -> mean/rstd ------------
__global__ void finalize_stats(float* __restrict__ st, int n, float inv) {
  int i = blockIdx.x * 256 + threadIdx.x;
  if (i >= n) return;
  float S = st[i * 2], SS = st[i * 2 + 1];
  float mean = S * inv;
  float var = SS * inv - mean * mean;
  st[i * 2] = mean;
  st[i * 2 + 1] = rsqrtf(var + 1e-5f);
}

// ---------------- combine -> bf16 channels-last ----------------------------
__global__ __launch_bounds__(256) void combine_cl(
    const float* __restrict__ x, const bf16* __restrict__ ys,
    const float* __restrict__ st, const float* __restrict__ gns,
    const float* __restrict__ gnb, const float* __restrict__ wts,
    bf16* __restrict__ ccl) {
  __shared__ bf16 tile[64][132];
  int b = blockIdx.x >> 6, h = blockIdx.x & 63;
  int t = threadIdx.x;
  int w32 = t & 31, coq = t >> 5;
  float m_[8], r_[8];
#pragma unroll
  for (int e = 0; e < 8; ++e) {
    m_[e] = st[((e * 16 + b) * 8 + coq) * 2];
    r_[e] = st[((e * 16 + b) * 8 + coq) * 2 + 1];
  }
#pragma unroll
  for (int wt2 = 0; wt2 < 2; ++wt2) {
    int w = wt2 * 32 + w32;
    int pid = (h >> 4) * 4 + (w >> 4);
    int pos = h * 64 + w;
    float wt_[8];
#pragma unroll
    for (int e = 0; e < 8; ++e) wt_[e] = wts[pid * 8 + e];
    for (int coi = 0; coi < 16; ++coi) {
      int co = coq * 16 + coi;
      float v = x[((size_t)(b * 128 + co) << 12) + pos];
#pragma unroll
      for (int e = 0; e < 8; ++e) {
        float y = bf2f(ys[((size_t)((e * 16 + b) * 128 + co) << 12) + pos]);
        float yn = (y - m_[e]) * r_[e] * gns[e * 128 + co] + gnb[e * 128 + co];
        v += siluf(yn) * wt_[e];
      }
      tile[w][co] = f2bf(v);
    }
  }
  __syncthreads();
  int row = t >> 2, q = t & 3;
  char* dst = (char*)ccl + ((size_t)(b * 4096 + h * 64 + row)) * 256 + q * 64;
  const char* src = (const char*)&tile[row][0] + q * 64;
#pragma unroll
  for (int i = 0; i < 4; ++i)
    *(uint4*)(dst + i * 16) = *(const uint4*)(src + i * 16);
}

// ---------------- pw1 MFMA: h1[hc=512][n=65536] = w[hc][ci] @ ccl[n][ci] ---
__global__ __launch_bounds__(256) void pw1_mfma(
    const bf16* __restrict__ ccl, const bf16* __restrict__ wp1T,
    bf16* __restrict__ h1cl, float* __restrict__ stats1) {
  __shared__ __align__(16) char ls[65536];  // als 32K | bls 32K ; reused as tile
  __shared__ float red[4][2][2];
  char* als = ls;
  char* bls = ls + 32768;
  int blk = blockIdx.x;
  int ntile = blk & 511, mtile = blk >> 9;
  int n0 = ntile * 128, m0 = mtile * 128;
  int t = threadIdx.x, lane = t & 63, wave = t >> 6;
  int quad = lane >> 4, l15 = lane & 15;
  int b = n0 >> 12;

#pragma unroll
  for (int i = 0; i < 8; ++i) {
    int id = t + 256 * i;
    int r = id >> 4, c = id & 15;
    *(uint4*)(als + c * 2048 + r * 16) =
        *(const uint4*)((const char*)wp1T + (size_t)(m0 + r) * 256 + c * 16);
    *(uint4*)(bls + c * 2048 + r * 16) =
        *(const uint4*)((const char*)ccl + (size_t)(n0 + r) * 256 + c * 16);
  }
  __syncthreads();

  f32x4 acc[8][2];
#pragma unroll
  for (int mt = 0; mt < 8; ++mt)
#pragma unroll
    for (int nt = 0; nt < 2; ++nt) acc[mt][nt] = (f32x4){0.f, 0.f, 0.f, 0.f};

#pragma unroll
  for (int kc = 0; kc < 4; ++kc) {
    int cgq = kc * 4 + quad;
    bf16x8 af[8];
#pragma unroll
    for (int mt = 0; mt < 8; ++mt)
      af[mt] = *(const bf16x8*)(als + cgq * 2048 + (mt * 16 + l15) * 16);
    bf16x8 bfr[2];
#pragma unroll
    for (int nt = 0; nt < 2; ++nt)
      bfr[nt] = *(const bf16x8*)(bls + cgq * 2048 + (wave * 32 + nt * 16 + l15) * 16);
#pragma unroll
    for (int mt = 0; mt < 8; ++mt)
#pragma unroll
      for (int nt = 0; nt < 2; ++nt)
        acc[mt][nt] = __builtin_amdgcn_mfma_f32_16x16x32_bf16(
            af[mt], bfr[nt], acc[mt][nt], 0, 0, 0);
  }

  __syncthreads();  // everyone done with als/bls
  float s[2] = {0.f, 0.f}, ss[2] = {0.f, 0.f};
  bf16* tile = (bf16*)ls;  // row stride 132 elems = 264 B
#pragma unroll
  for (int mt = 0; mt < 8; ++mt) {
    int gi = mt >> 2;
#pragma unroll
    for (int nt = 0; nt < 2; ++nt) {
      int n = wave * 32 + nt * 16 + l15;
#pragma unroll
      for (int r = 0; r < 4; ++r) {
        float v = acc[mt][nt][r];
        s[gi] += v;
        ss[gi] += v * v;
        tile[n * 132 + mt * 16 + quad * 4 + r] = f2bf(v);
      }
    }
  }
#pragma unroll
  for (int gi = 0; gi < 2; ++gi) {
#pragma unroll
    for (int off = 32; off; off >>= 1) {
      s[gi] += __shfl_down(s[gi], off, 64);
      ss[gi] += __shfl_down(ss[gi], off, 64);
    }
  }
  if (lane == 0) {
    red[wave][0][0] = s[0]; red[wave][0][1] = ss[0];
    red[wave][1][0] = s[1]; red[wave][1][1] = ss[1];
  }
  __syncthreads();
  if (t < 4) {
    int gi = t >> 1, which = t & 1;
    float v = red[0][gi][which] + red[1][gi][which] + red[2][gi][which] + red[3][gi][which];
    atomicAdd(&stats1[(b * 8 + mtile * 2 + gi) * 2 + which], v);
  }
#pragma unroll
  for (int i = 0; i < 8; ++i) {
    int id = t + 256 * i;             // 0..2047
    int r = id >> 4, q = id & 15;     // 128 rows x 16 chunks of 16B
    char* dst = (char*)h1cl + (size_t)(n0 + r) * 1024 + m0 * 2 + q * 16;
    const char* src = (const char*)tile + r * 264 + q * 16;
    *(uint4*)dst = *(const uint4*)src;
  }
}

// ---------------- dw3x3 v2: LDS-staged GN1+SiLU tile + sliding stencil -----
__global__ __launch_bounds__(256) void dw_cl(
    const bf16* __restrict__ h1cl, const float* __restrict__ w_dw,
    const float* __restrict__ st1, const float* __restrict__ gs,
    const float* __restrict__ gb, bf16* __restrict__ h2cl,
    float* __restrict__ stats2) {
  __shared__ __align__(16) bf16 tile[18 * 66 * 16];  // 38016 B
  __shared__ float red2[4][2];
  int blk = blockIdx.x;
  int ht = blk & 3, hcg = (blk >> 2) & 31, b = blk >> 7;
  int h0 = ht * 16;
  int hc0 = hcg * 16;
  int hcb = hcg >> 2;  // 64-hc GN group
  int t = threadIdx.x;

  float mean = st1[(b * 8 + hcb) * 2], rstd = st1[(b * 8 + hcb) * 2 + 1];
  float scale[16], shift[16];
#pragma unroll
  for (int j = 0; j < 16; ++j) {
    float g = gs[hc0 + j];
    scale[j] = rstd * g;
    shift[j] = gb[hc0 + j] - mean * rstd * g;
  }

  for (int i = 0; i < 5; ++i) {
    int idx = t + 256 * i;
    if (idx >= 1188) break;
    int row = idx / 66, wslot = idx - row * 66;
    int hh = h0 - 1 + row;
    int w = wslot - 1;
    int swz = (wslot >> 2) & 3;
    bf16* dst = tile + (row * 66 + wslot) * 16;
    if ((unsigned)hh < 64u && (unsigned)w < 64u) {
      const char* p = (const char*)h1cl + ((size_t)(b * 4096 + hh * 64 + w) * 512 + hc0) * 2;
      uint4 a0 = *(const uint4*)p;
      uint4 a1 = *(const uint4*)(p + 16);
      const bf16* pv = (const bf16*)&a0;
      const bf16* pv1 = (const bf16*)&a1;
      bf16 outv[16];
#pragma unroll
      for (int j = 0; j < 8; ++j)
        outv[j] = f2bf(siluf(bf2f(pv[j]) * scale[j] + shift[j]));
#pragma unroll
      for (int j = 0; j < 8; ++j)
        outv[8 + j] = f2bf(siluf(bf2f(pv1[j]) * scale[8 + j] + shift[8 + j]));
#pragma unroll
      for (int qq = 0; qq < 4; ++qq) {
        int ph = (qq + swz) & 3;
        *(uint2*)(dst + ph * 4) = *(const uint2*)(outv + qq * 4);
      }
    } else {
      *(uint4*)dst = make_uint4(0u, 0u, 0u, 0u);
      *(uint4*)(dst + 8) = make_uint4(0u, 0u, 0u, 0u);
    }
  }
  __syncthreads();

  int w = t & 63, q = t >> 6;
  float wv[9][4];
#pragma unroll
  for (int j = 0; j < 4; ++j) {
    int hc = hc0 + q * 4 + j;
#pragma unroll
    for (int tap = 0; tap < 9; ++tap) wv[tap][j] = w_dw[hc * 9 + tap];
  }

  f32x4 win[3][3];
  float acc_s = 0.f, acc_ss = 0.f;

  auto ld4 = [&](int r, int dwi) -> f32x4 {
    int slot = w + dwi;
    int ph = (q + (slot >> 2)) & 3;
    const bf16* p = tile + (r * 66 + slot) * 16 + ph * 4;
    uint2 u = *(const uint2*)p;
    const bf16* pb = (const bf16*)&u;
    return (f32x4){bf2f(pb[0]), bf2f(pb[1]), bf2f(pb[2]), bf2f(pb[3])};
  };

#pragma unroll
  for (int dwi = 0; dwi < 3; ++dwi) {
    win[0][dwi] = ld4(0, dwi);
    win[1][dwi] = ld4(1, dwi);
  }
#pragma unroll
  for (int orow = 0; orow < 16; ++orow) {
    int rnew = orow + 2;
    int ringn = rnew % 3;
#pragma unroll
    for (int dwi = 0; dwi < 3; ++dwi) win[ringn][dwi] = ld4(rnew, dwi);
    f32x4 acc = (f32x4){0.f, 0.f, 0.f, 0.f};
#pragma unroll
    for (int dr = 0; dr < 3; ++dr) {
      int ring = (orow + dr) % 3;
#pragma unroll
      for (int dwi = 0; dwi < 3; ++dwi) {
#pragma unroll
        for (int j = 0; j < 4; ++j)
          acc[j] = fmaf(win[ring][dwi][j], wv[dr * 3 + dwi][j], acc[j]);
      }
    }
#pragma unroll
    for (int j = 0; j < 4; ++j) { acc_s += acc[j]; acc_ss += acc[j] * acc[j]; }
    if (!(orow & 1) && !(w & 1)) {
      int hglob = h0 + orow;
      int pos2 = (hglob >> 1) * 32 + (w >> 1);
      bf16 tmp[4];
#pragma unroll
      for (int j = 0; j < 4; ++j) tmp[j] = f2bf(acc[j]);
      *(uint2*)((char*)h2cl + ((size_t)(b * 1024 + pos2) * 512 + hc0 + q * 4) * 2) =
          *(const uint2*)tmp;
    }
  }

#pragma unroll
  for (int off = 32; off; off >>= 1) {
    acc_s += __shfl_down(acc_s, off, 64);
    acc_ss += __shfl_down(acc_ss, off, 64);
  }
  int wave = t >> 6;
  if ((t & 63) == 0) { red2[wave][0] = acc_s; red2[wave][1] = acc_ss; }
  __syncthreads();
  if (t < 2) {
    float v = red2[0][t] + red2[1][t] + red2[2][t] + red2[3][t];
    atomicAdd(&stats2[(b * 8 + hcb) * 2 + t], v);
  }
}

// ---------------- pw2 MFMA with fused GN2+SiLU on B staging ----------------
// h3[co=128][n=16384] = w[co][hc] @ silu(gn2(h2raw))[n][hc]
__global__ __launch_bounds__(256) void pw2_mfma(
    const bf16* __restrict__ h2raw, const bf16* __restrict__ wp2T,
    const float* __restrict__ st2, const float* __restrict__ gs2,
    const float* __restrict__ gb2, float* __restrict__ h3,
    float* __restrict__ stats3) {
  __shared__ __align__(16) char als[2][8192];
  __shared__ __align__(16) char bls[2][4096];
  __shared__ float red[4][8][2];
  int blk = blockIdx.x;
  int n0 = blk * 64;
  int b = n0 >> 10, posb = n0 & 1023;
  int t = threadIdx.x, lane = t & 63, wave = t >> 6;
  int quad = lane >> 4, l15 = lane & 15;
  int wbase = wave * 16;

  f32x4 acc[8];
#pragma unroll
  for (int mt = 0; mt < 8; ++mt) acc[mt] = (f32x4){0.f, 0.f, 0.f, 0.f};

  // B staging with fused normalize+SiLU (each h2 element staged exactly once)
  auto stageB = [&](int buf, int kc) {
    int c4 = t >> 6, r = t & 63;
    int hcb = (kc * 4 + c4) * 8;
    int g = hcb >> 6;
    float mean = st2[(b * 8 + g) * 2], rstd = st2[(b * 8 + g) * 2 + 1];
    uint4 raw = *(const uint4*)((const char*)h2raw + (size_t)(n0 + r) * 1024 + (kc * 4 + c4) * 16);
    const bf16* pv = (const bf16*)&raw;
    bf16 outv[8];
#pragma unroll
    for (int j = 0; j < 8; ++j) {
      float v = bf2f(pv[j]);
      v = (v - mean) * rstd * gs2[hcb + j] + gb2[hcb + j];
      outv[j] = f2bf(siluf(v));
    }
    *(uint4*)(bls[buf] + c4 * 1024 + r * 16) = *(const uint4*)outv;
  };

  {
#pragma unroll
    for (int i = 0; i < 2; ++i) {
      int id = t + 256 * i;
      int c4 = id >> 7, r = id & 127;
      *(uint4*)(als[0] + c4 * 2048 + r * 16) =
          *(const uint4*)((const char*)wp2T + (size_t)r * 1024 + c4 * 16);
    }
    stageB(0, 0);
  }
  for (int kc = 0; kc < 16; ++kc) {
    __syncthreads();
    if (kc + 1 < 16) {
      int nb = (kc + 1) & 1;
#pragma unroll
      for (int i = 0; i < 2; ++i) {
        int id = t + 256 * i;
        int c4 = id >> 7, r = id & 127;
        *(uint4*)(als[nb] + c4 * 2048 + r * 16) =
            *(const uint4*)((const char*)wp2T + (size_t)r * 1024 + ((kc + 1) * 4 + c4) * 16);
      }
      stageB(nb, kc + 1);
    }
    int buf = kc & 1;
    bf16x8 bf1 = *(const bf16x8*)(bls[buf] + quad * 1024 + (wbase + l15) * 16);
#pragma unroll
    for (int mt = 0; mt < 8; ++mt) {
      bf16x8 af = *(const bf16x8*)(als[buf] + quad * 2048 + (mt * 16 + l15) * 16);
      acc[mt] = __builtin_amdgcn_mfma_f32_16x16x32_bf16(af, bf1, acc[mt], 0, 0, 0);
    }
  }

#pragma unroll
  for (int mt = 0; mt < 8; ++mt) {
    float s = 0.f, ss = 0.f;
    int pos = posb + wbase + l15;
#pragma unroll
    for (int r = 0; r < 4; ++r) {
      float v = acc[mt][r];
      s += v;
      ss += v * v;
      int co = mt * 16 + quad * 4 + r;
      h3[(size_t)(b * 128 + co) * 1024 + pos] = v;
    }
#pragma unroll
    for (int off = 32; off; off >>= 1) {
      s += __shfl_down(s, off, 64);
      ss += __shfl_down(ss, off, 64);
    }
    if (lane == 0) { red[wave][mt][0] = s; red[wave][mt][1] = ss; }
  }
  __syncthreads();
  if (t < 16) {
    int mt = t >> 1, which = t & 1;
    float v = red[0][mt][which] + red[1][mt][which] + red[2][mt][which] + red[3][mt][which];
    atomicAdd(&stats3[(b * 8 + mt) * 2 + which], v);
  }
}

// ---------------- final GN+SiLU -> d_out (fp32) ----------------------------
__global__ void out_kernel(const float* __restrict__ h3, const float* __restrict__ stats,
                           const float* __restrict__ gs, const float* __restrict__ gb,
                           float* __restrict__ out) {
  const int total = B_ * COUT_ * 1024;
  for (int idx = blockIdx.x * blockDim.x + threadIdx.x; idx < total; idx += gridDim.x * blockDim.x) {
    int c = (idx >> 10) & 127;
    int b = idx >> 17;
    int bg = b * 8 + (c >> 4);
    float S = stats[bg * 2], SS = stats[bg * 2 + 1];
    float mean = S * (1.f / 16384.f);
    float var = SS * (1.f / 16384.f) - mean * mean;
    float rstd = rsqrtf(var + 1e-5f);
    float v = (h3[idx] - mean) * rstd * gs[c] + gb[c];
    out[idx] = siluf(v);
  }
}

extern "C" void kernel_launch(void* const* d_in, const int* in_sizes, int n_in,
                              void* d_out, int out_size, void* d_ws, size_t ws_size,
                              hipStream_t stream) {
  const float* x = (const float*)d_in[0];
  const float* w_exp = (const float*)d_in[1];
  const float* gn_exp_s = (const float*)d_in[2];
  const float* gn_exp_b = (const float*)d_in[3];
  const float* w1 = (const float*)d_in[4];
  const float* b1 = (const float*)d_in[5];
  const float* w2 = (const float*)d_in[6];
  const float* b2 = (const float*)d_in[7];
  const float* w_pw1 = (const float*)d_in[8];
  const float* gn1_s = (const float*)d_in[9];
  const float* gn1_b = (const float*)d_in[10];
  const float* w_dw = (const float*)d_in[11];
  const float* gn2_s = (const float*)d_in[12];
  const float* gn2_b = (const float*)d_in[13];
  const float* w_pw2 = (const float*)d_in[14];
  const float* gn3_s = (const float*)d_in[15];
  const float* gn3_b = (const float*)d_in[16];

  char* ws = (char*)d_ws;
  const size_t WP1T_OFF = 16384;
  const size_t WP2T_OFF = WP1T_OFF + 131072;
  const size_t XT_OFF = WP2T_OFF + 131072;                 // 278528
  const size_t WT_OFF = XT_OFF + 16777216;                 // 17055744
  const size_t YS_OFF = WT_OFF + 2359296;                  // 19415040
  const size_t NEEDED = YS_OFF + 134217728;                // 153632768
  if (ws_size < NEEDED) return;

  float* wts = (float*)ws;
  float* stats1 = (float*)(ws + 1024);
  float* stats2 = (float*)(ws + 2048);
  float* stats3 = (float*)(ws + 3072);
  float* statsE = (float*)(ws + 4096);
  bf16* wp1T = (bf16*)(ws + WP1T_OFF);
  bf16* wp2T = (bf16*)(ws + WP2T_OFF);
  bf16* xT = (bf16*)(ws + XT_OFF);
  bf16* ccl = (bf16*)(ws + XT_OFF);
  bf16* wT = (bf16*)(ws + WT_OFF);
  bf16* ys = (bf16*)(ws + YS_OFF);
  bf16* h1cl = (bf16*)(ws + YS_OFF);
  bf16* h2cl = (bf16*)(ws + YS_OFF + 67108864);
  float* h3 = (float*)(ws + YS_OFF + 83886080);

  hipMemsetAsync(ws, 0, 16384, stream);
  gate_kernel<<<1, 64, 0, stream>>>(w1, b1, w2, b2, wts);
  xt_kernel<<<B_ * 64, 256, 0, stream>>>(x, xT);
  wt_kernel<<<4608, 256, 0, stream>>>(w_exp, wT);
  wpT_kernel<<<512, 256, 0, stream>>>(w_pw1, w_pw2, wp1T, wp2T);
  conv_mfma<<<E_ * B_ * 16, 256, 0, stream>>>(xT, wT, statsE, ys);
  finalize_stats<<<4, 256, 0, stream>>>(statsE, 1024, 1.f / 65536.f);
  combine_cl<<<B_ * 64, 256, 0, stream>>>(x, ys, statsE, gn_exp_s, gn_exp_b, wts, ccl);
  pw1_mfma<<<4 * 512, 256, 0, stream>>>(ccl, wp1T, h1cl, stats1);
  finalize_stats<<<1, 128, 0, stream>>>(stats1, 128, 1.f / 262144.f);
  dw_cl<<<B_ * 32 * 4, 256, 0, stream>>>(h1cl, w_dw, stats1, gn1_s, gn1_b, h2cl, stats2);
  finalize_stats<<<1, 128, 0, stream>>>(stats2, 128, 1.f / 262144.f);
  pw2_mfma<<<256, 256, 0, stream>>>(h2cl, wp2T, stats2, gn2_s, gn2_b, h3, stats3);
  out_kernel<<<1024, 256, 0, stream>>>(h3, stats3, gn3_s, gn3_b, (float*)d_out);
}

// Round 8
// 552.030 us; speedup vs baseline: 1.0374x; 1.0374x over previous
//
#include <hip/hip_runtime.h>
#include <hip/hip_bf16.h>

// ---------------------------------------------------------------------------
// PCELayer R8.
//  conv_mfma v4: 2-row tiles (acc 64 regs), W DOUBLE-BUFFERED IN LDS staged
//  by global_load_lds issued after each tap's barrier (flies during MFMA;
//  next barrier's vmcnt(0) drain is free). One barrier per tap. X staged via
//  global_load_lds per ci-half. LDS 64.5 KB -> 2 blocks/CU.
//  R6/R7 lesson: register prefetch spills (acc128+112 VGPR = 240/256 budget;
//  +16 regs => scratch traffic +85MB). Pipeline state must live in LDS.
//  Rest identical to R7 (pw2 fuses GN2+SiLU; no norm2 kernel).
// Workspace (153.6 MB): head 16K | wp1T 128K | wp2T 128K | XT 16.8M | WT 2.4M
//   | YS 134.2M (-> h1cl 67M | h2cl 16.8M | h3 8.4M)
// ---------------------------------------------------------------------------

#define B_ 16
#define CIN_ 128
#define COUT_ 128
#define H_ 64
#define W_ 64
#define HW_ 4096
#define E_ 8
#define FF_ 8
#define GC_ 32
#define HID_ 64
#define HC_ 512

typedef __hip_bfloat16 bf16;
typedef __bf16 bf16x8 __attribute__((ext_vector_type(8)));
typedef float f32x4 __attribute__((ext_vector_type(4)));

__device__ __forceinline__ float siluf(float v) { return v / (1.f + __expf(-v)); }
__device__ __forceinline__ float bf2f(bf16 v) { return __bfloat162float(v); }
__device__ __forceinline__ bf16 f2bf(float v) { return __float2bfloat16(v); }

__device__ __forceinline__ void async_copy16(void* lds, const void* g) {
  __builtin_amdgcn_global_load_lds(
      (const __attribute__((address_space(1))) unsigned int*)g,
      (__attribute__((address_space(3))) unsigned int*)lds, 16, 0, 0);
}

// ---------------- router gate ----------------------------------------------
__global__ void gate_kernel(const float* __restrict__ w1, const float* __restrict__ b1,
                            const float* __restrict__ w2, const float* __restrict__ b2,
                            float* __restrict__ wts) {
  int p = threadIdx.x;
  if (p >= 16) return;
  int i = p >> 2, j = p & 3;
  float cy = (i + 0.5f) * 0.25f;
  float cx = (j + 0.5f) * 0.25f;
  float feats[GC_];
#pragma unroll
  for (int f = 0; f < FF_; ++f) {
    float fr = 3.14159265358979f * (float)(1 << f);
    float ay = cy * fr, ax = cx * fr;
    feats[f] = sinf(ay);
    feats[FF_ + f] = cosf(ay);
    feats[2 * FF_ + f] = sinf(ax);
    feats[3 * FF_ + f] = cosf(ax);
  }
  float hid[HID_];
  for (int k = 0; k < HID_; ++k) {
    float a = b1[k];
#pragma unroll
    for (int m = 0; m < GC_; ++m) a = fmaf(feats[m], w1[m * HID_ + k], a);
    hid[k] = siluf(a);
  }
  float lg[E_];
  float mx = -1e30f;
#pragma unroll
  for (int e = 0; e < E_; ++e) {
    float a = b2[e];
    for (int k = 0; k < HID_; ++k) a = fmaf(hid[k], w2[k * E_ + e], a);
    lg[e] = a;
    mx = fmaxf(mx, a);
  }
  float s = 0.f;
#pragma unroll
  for (int e = 0; e < E_; ++e) { lg[e] = __expf(lg[e] - mx); s += lg[e]; }
  float inv = 1.f / s;
#pragma unroll
  for (int e = 0; e < E_; ++e) wts[p * E_ + e] = lg[e] * inv;
}

// ---------------- x -> channels-last bf16 ----------------------------------
__global__ __launch_bounds__(256) void xt_kernel(const float* __restrict__ x,
                                                 bf16* __restrict__ xT) {
  __shared__ float t[128][65];
  int b = blockIdx.x >> 6, h = blockIdx.x & 63;
  int tid = threadIdx.x;
  int w = tid & 63, c4 = tid >> 6;
  const float* xb = x + ((size_t)(b * 128) * 64 + h) * 64;
#pragma unroll 4
  for (int rep = 0; rep < 32; ++rep) {
    int ci = rep * 4 + c4;
    t[ci][w] = xb[(size_t)ci * HW_ + w];
  }
  __syncthreads();
  bf16* dst = xT + (size_t)(b * 64 + h) * 8192;
#pragma unroll 4
  for (int rep = 0; rep < 32; ++rep) {
    int o = rep * 256 + tid;
    int cg = o >> 9, w2 = (o >> 3) & 63, lo = o & 7;
    dst[o] = f2bf(t[cg * 8 + lo][w2]);
  }
}

// ---------------- w_exp -> wT bf16 -----------------------------------------
__global__ void wt_kernel(const float* __restrict__ w_exp, bf16* __restrict__ wT) {
  int idx = blockIdx.x * 256 + threadIdx.x;
  if (idx >= 1179648) return;
  int lo = idx & 7;
  int co = (idx >> 3) & 127;
  int cg = (idx >> 10) & 15;
  int rest = idx >> 14;
  int tap = rest % 9, e = rest / 9;
  int ci = cg * 8 + lo;
  wT[idx] = f2bf(w_exp[(((size_t)(e * 128 + co) * 128 + ci) * 9) + tap]);
}

// ---------------- pw weights fp32 -> bf16 ----------------------------------
__global__ void wpT_kernel(const float* __restrict__ w_pw1, const float* __restrict__ w_pw2,
                           bf16* __restrict__ wp1T, bf16* __restrict__ wp2T) {
  int idx = blockIdx.x * 256 + threadIdx.x;
  if (idx < 65536) wp1T[idx] = f2bf(w_pw1[idx]);
  else if (idx < 131072) wp2T[idx - 65536] = f2bf(w_pw2[idx - 65536]);
}

// ---------------- expert conv via MFMA (v4: LDS-dbuf W pipeline) -----------
// grid: e(8) x b(16) x rt(32 tiles of 2 rows). 256 thr = 4 waves.
// Block: 128co x 128pos (2 rows x 64 w). Wave: row wave>>1, wbase (wave&1)*32,
// 8mt x 2nt of 16x16x32. kt = half*9+tap in 0..17; W in wls[kt&1], next tap's
// W DMA'd into wls[(kt+1)&1] right after the barrier.
__global__ __launch_bounds__(256, 2) void conv_mfma(
    const bf16* __restrict__ xT, const bf16* __restrict__ wT,
    float* __restrict__ statsE, bf16* __restrict__ ys) {
  __shared__ __align__(16) char xls[8 * 4096];     // [cg(8)][r(4)][w(64)]x16B = 32K
  __shared__ __align__(16) char wls[2][16384];     // [cg(8)][co(128)]x16B each
  __shared__ float red[4][8][2];

  int blk = blockIdx.x;
  int rt = blk & 31, b = (blk >> 5) & 15, e = blk >> 9;
  int tid = threadIdx.x, lane = tid & 63, wave = tid >> 6;
  int quad = lane >> 4, l15 = lane & 15;
  int h0 = rt * 2;
  int h_local = wave >> 1, wbase = (wave & 1) * 32;

  f32x4 acc[8][2];
#pragma unroll
  for (int mt = 0; mt < 8; ++mt)
#pragma unroll
    for (int nt = 0; nt < 2; ++nt) acc[mt][nt] = (f32x4){0.f, 0.f, 0.f, 0.f};

  bf16x8 bz;
#pragma unroll
  for (int j = 0; j < 8; ++j) bz[j] = (__bf16)0.f;

  // W DMA: one tap's 16KB into wls[buf]; 4 segs of 1KB per wave.
  auto wdma = [&](int kt2, int buf) {
    int hf = kt2 / 9, tp = kt2 - hf * 9;
#pragma unroll
    for (int s = 0; s < 4; ++s) {
      int seg = wave * 4 + s;
      int cg = seg >> 1, cb = seg & 1;
      const char* g = (const char*)wT +
          (size_t)(((e * 9 + tp) * 16) + hf * 8 + cg) * 2048 + cb * 1024 + lane * 16;
      async_copy16(wls[buf] + cg * 2048 + cb * 1024 + lane * 16, g);
    }
  };
  // X DMA: one ci-half's 32KB (8cg x 4r); 8 segs of 1KB per wave.
  auto xdma = [&](int half) {
#pragma unroll
    for (int s = 0; s < 8; ++s) {
      int seg = wave * 8 + s;
      int cg = seg >> 2, r = seg & 3;
      int h = h0 - 1 + r;
      char* ldst = xls + cg * 4096 + r * 1024 + lane * 16;
      if ((unsigned)h < 64u) {
        const char* g = (const char*)xT +
            ((size_t)((b * 64 + h) * 16) + half * 8 + cg) * 1024 + lane * 16;
        async_copy16(ldst, g);
      } else {
        *(uint4*)ldst = make_uint4(0u, 0u, 0u, 0u);
      }
    }
  };

  wdma(0, 0);
  xdma(0);

  for (int kt = 0; kt < 18; ++kt) {
    if (kt == 9) {
      __syncthreads();  // all half-0 xls reads done
      xdma(1);
    }
    __syncthreads();  // drains W DMA (issued last tap -> free) + X DMA
    if (kt + 1 < 18) wdma(kt + 1, (kt + 1) & 1);  // flies during this tap's MFMA
    int tap = kt % 9;
    int dr = tap / 3, ds = tap % 3;
    int r_local = h_local + dr;
    const char* wb = wls[kt & 1];
#pragma unroll
    for (int kc = 0; kc < 2; ++kc) {
      int cgq = kc * 4 + quad;
      bf16x8 af[8];
#pragma unroll
      for (int mt = 0; mt < 8; ++mt)
        af[mt] = *(const bf16x8*)(wb + cgq * 2048 + (mt * 16 + l15) * 16);
      bf16x8 bfr[2];
#pragma unroll
      for (int nt = 0; nt < 2; ++nt) {
        int w = wbase + nt * 16 + l15;
        int wsrc = w + ds - 1;
        bool valid = (unsigned)wsrc < 64u;
        int wc = valid ? wsrc : 0;
        bf16x8 v = *(const bf16x8*)(xls + cgq * 4096 + (r_local * 64 + wc) * 16);
        bfr[nt] = valid ? v : bz;
      }
#pragma unroll
      for (int mt = 0; mt < 8; ++mt)
#pragma unroll
        for (int nt = 0; nt < 2; ++nt)
          acc[mt][nt] = __builtin_amdgcn_mfma_f32_16x16x32_bf16(
              af[mt], bfr[nt], acc[mt][nt], 0, 0, 0);
    }
  }

  // epilogue: raw ys + GN partial stats (group g = mt since co>>4 = mt)
  int hh = h0 + h_local;
  bf16* yb = ys + (size_t)((e * 16 + b) * 128) * 4096;
#pragma unroll
  for (int mt = 0; mt < 8; ++mt) {
    float s = 0.f, ss = 0.f;
#pragma unroll
    for (int nt = 0; nt < 2; ++nt) {
      int w = wbase + nt * 16 + l15;
      int pos = hh * 64 + w;
#pragma unroll
      for (int r = 0; r < 4; ++r) {
        float v = acc[mt][nt][r];
        s += v;
        ss += v * v;
        int co = mt * 16 + quad * 4 + r;
        yb[(size_t)co * 4096 + pos] = f2bf(v);
      }
    }
#pragma unroll
    for (int off = 32; off; off >>= 1) {
      s += __shfl_down(s, off, 64);
      ss += __shfl_down(ss, off, 64);
    }
    if (lane == 0) { red[wave][mt][0] = s; red[wave][mt][1] = ss; }
  }
  __syncthreads();
  if (tid < 16) {
    int g = tid >> 1, which = tid & 1;
    float t = red[0][g][which] + red[1][g][which] + red[2][g][which] + red[3][g][which];
    atomicAdd(&statsE[((e * 16 + b) * 8 + g) * 2 + which], t);
  }
}

// ---------------- generic stats finalize: raw S/SS -> mean/rstd ------------
__global__ void finalize_stats(float* __restrict__ st, int n, float inv) {
  int i = blockIdx.x * 256 + threadIdx.x;
  if (i >= n) return;
  float S = st[i * 2], SS = st[i * 2 + 1];
  float mean = S * inv;
  float var = SS * inv - mean * mean;
  st[i * 2] = mean;
  st[i * 2 + 1] = rsqrtf(var + 1e-5f);
}

// ---------------- combine -> bf16 channels-last ----------------------------
__global__ __launch_bounds__(256) void combine_cl(
    const float* __restrict__ x, const bf16* __restrict__ ys,
    const float* __restrict__ st, const float* __restrict__ gns,
    const float* __restrict__ gnb, const float* __restrict__ wts,
    bf16* __restrict__ ccl) {
  __shared__ bf16 tile[64][132];
  int b = blockIdx.x >> 6, h = blockIdx.x & 63;
  int t = threadIdx.x;
  int w32 = t & 31, coq = t >> 5;
  float m_[8], r_[8];
#pragma unroll
  for (int e = 0; e < 8; ++e) {
    m_[e] = st[((e * 16 + b) * 8 + coq) * 2];
    r_[e] = st[((e * 16 + b) * 8 + coq) * 2 + 1];
  }
#pragma unroll
  for (int wt2 = 0; wt2 < 2; ++wt2) {
    int w = wt2 * 32 + w32;
    int pid = (h >> 4) * 4 + (w >> 4);
    int pos = h * 64 + w;
    float wt_[8];
#pragma unroll
    for (int e = 0; e < 8; ++e) wt_[e] = wts[pid * 8 + e];
    for (int coi = 0; coi < 16; ++coi) {
      int co = coq * 16 + coi;
      float v = x[((size_t)(b * 128 + co) << 12) + pos];
#pragma unroll
      for (int e = 0; e < 8; ++e) {
        float y = bf2f(ys[((size_t)((e * 16 + b) * 128 + co) << 12) + pos]);
        float yn = (y - m_[e]) * r_[e] * gns[e * 128 + co] + gnb[e * 128 + co];
        v += siluf(yn) * wt_[e];
      }
      tile[w][co] = f2bf(v);
    }
  }
  __syncthreads();
  int row = t >> 2, q = t & 3;
  char* dst = (char*)ccl + ((size_t)(b * 4096 + h * 64 + row)) * 256 + q * 64;
  const char* src = (const char*)&tile[row][0] + q * 64;
#pragma unroll
  for (int i = 0; i < 4; ++i)
    *(uint4*)(dst + i * 16) = *(const uint4*)(src + i * 16);
}

// ---------------- pw1 MFMA: h1[hc=512][n=65536] = w[hc][ci] @ ccl[n][ci] ---
__global__ __launch_bounds__(256) void pw1_mfma(
    const bf16* __restrict__ ccl, const bf16* __restrict__ wp1T,
    bf16* __restrict__ h1cl, float* __restrict__ stats1) {
  __shared__ __align__(16) char ls[65536];  // als 32K | bls 32K ; reused as tile
  __shared__ float red[4][2][2];
  char* als = ls;
  char* bls = ls + 32768;
  int blk = blockIdx.x;
  int ntile = blk & 511, mtile = blk >> 9;
  int n0 = ntile * 128, m0 = mtile * 128;
  int t = threadIdx.x, lane = t & 63, wave = t >> 6;
  int quad = lane >> 4, l15 = lane & 15;
  int b = n0 >> 12;

#pragma unroll
  for (int i = 0; i < 8; ++i) {
    int id = t + 256 * i;
    int r = id >> 4, c = id & 15;
    *(uint4*)(als + c * 2048 + r * 16) =
        *(const uint4*)((const char*)wp1T + (size_t)(m0 + r) * 256 + c * 16);
    *(uint4*)(bls + c * 2048 + r * 16) =
        *(const uint4*)((const char*)ccl + (size_t)(n0 + r) * 256 + c * 16);
  }
  __syncthreads();

  f32x4 acc[8][2];
#pragma unroll
  for (int mt = 0; mt < 8; ++mt)
#pragma unroll
    for (int nt = 0; nt < 2; ++nt) acc[mt][nt] = (f32x4){0.f, 0.f, 0.f, 0.f};

#pragma unroll
  for (int kc = 0; kc < 4; ++kc) {
    int cgq = kc * 4 + quad;
    bf16x8 af[8];
#pragma unroll
    for (int mt = 0; mt < 8; ++mt)
      af[mt] = *(const bf16x8*)(als + cgq * 2048 + (mt * 16 + l15) * 16);
    bf16x8 bfr[2];
#pragma unroll
    for (int nt = 0; nt < 2; ++nt)
      bfr[nt] = *(const bf16x8*)(bls + cgq * 2048 + (wave * 32 + nt * 16 + l15) * 16);
#pragma unroll
    for (int mt = 0; mt < 8; ++mt)
#pragma unroll
      for (int nt = 0; nt < 2; ++nt)
        acc[mt][nt] = __builtin_amdgcn_mfma_f32_16x16x32_bf16(
            af[mt], bfr[nt], acc[mt][nt], 0, 0, 0);
  }

  __syncthreads();  // everyone done with als/bls
  float s[2] = {0.f, 0.f}, ss[2] = {0.f, 0.f};
  bf16* tile = (bf16*)ls;  // row stride 132 elems = 264 B
#pragma unroll
  for (int mt = 0; mt < 8; ++mt) {
    int gi = mt >> 2;
#pragma unroll
    for (int nt = 0; nt < 2; ++nt) {
      int n = wave * 32 + nt * 16 + l15;
#pragma unroll
      for (int r = 0; r < 4; ++r) {
        float v = acc[mt][nt][r];
        s[gi] += v;
        ss[gi] += v * v;
        tile[n * 132 + mt * 16 + quad * 4 + r] = f2bf(v);
      }
    }
  }
#pragma unroll
  for (int gi = 0; gi < 2; ++gi) {
#pragma unroll
    for (int off = 32; off; off >>= 1) {
      s[gi] += __shfl_down(s[gi], off, 64);
      ss[gi] += __shfl_down(ss[gi], off, 64);
    }
  }
  if (lane == 0) {
    red[wave][0][0] = s[0]; red[wave][0][1] = ss[0];
    red[wave][1][0] = s[1]; red[wave][1][1] = ss[1];
  }
  __syncthreads();
  if (t < 4) {
    int gi = t >> 1, which = t & 1;
    float v = red[0][gi][which] + red[1][gi][which] + red[2][gi][which] + red[3][gi][which];
    atomicAdd(&stats1[(b * 8 + mtile * 2 + gi) * 2 + which], v);
  }
#pragma unroll
  for (int i = 0; i < 8; ++i) {
    int id = t + 256 * i;             // 0..2047
    int r = id >> 4, q = id & 15;     // 128 rows x 16 chunks of 16B
    char* dst = (char*)h1cl + (size_t)(n0 + r) * 1024 + m0 * 2 + q * 16;
    const char* src = (const char*)tile + r * 264 + q * 16;
    *(uint4*)dst = *(const uint4*)src;
  }
}

// ---------------- dw3x3 v2: LDS-staged GN1+SiLU tile + sliding stencil -----
__global__ __launch_bounds__(256) void dw_cl(
    const bf16* __restrict__ h1cl, const float* __restrict__ w_dw,
    const float* __restrict__ st1, const float* __restrict__ gs,
    const float* __restrict__ gb, bf16* __restrict__ h2cl,
    float* __restrict__ stats2) {
  __shared__ __align__(16) bf16 tile[18 * 66 * 16];  // 38016 B
  __shared__ float red2[4][2];
  int blk = blockIdx.x;
  int ht = blk & 3, hcg = (blk >> 2) & 31, b = blk >> 7;
  int h0 = ht * 16;
  int hc0 = hcg * 16;
  int hcb = hcg >> 2;  // 64-hc GN group
  int t = threadIdx.x;

  float mean = st1[(b * 8 + hcb) * 2], rstd = st1[(b * 8 + hcb) * 2 + 1];
  float scale[16], shift[16];
#pragma unroll
  for (int j = 0; j < 16; ++j) {
    float g = gs[hc0 + j];
    scale[j] = rstd * g;
    shift[j] = gb[hc0 + j] - mean * rstd * g;
  }

  for (int i = 0; i < 5; ++i) {
    int idx = t + 256 * i;
    if (idx >= 1188) break;
    int row = idx / 66, wslot = idx - row * 66;
    int hh = h0 - 1 + row;
    int w = wslot - 1;
    int swz = (wslot >> 2) & 3;
    bf16* dst = tile + (row * 66 + wslot) * 16;
    if ((unsigned)hh < 64u && (unsigned)w < 64u) {
      const char* p = (const char*)h1cl + ((size_t)(b * 4096 + hh * 64 + w) * 512 + hc0) * 2;
      uint4 a0 = *(const uint4*)p;
      uint4 a1 = *(const uint4*)(p + 16);
      const bf16* pv = (const bf16*)&a0;
      const bf16* pv1 = (const bf16*)&a1;
      bf16 outv[16];
#pragma unroll
      for (int j = 0; j < 8; ++j)
        outv[j] = f2bf(siluf(bf2f(pv[j]) * scale[j] + shift[j]));
#pragma unroll
      for (int j = 0; j < 8; ++j)
        outv[8 + j] = f2bf(siluf(bf2f(pv1[j]) * scale[8 + j] + shift[8 + j]));
#pragma unroll
      for (int qq = 0; qq < 4; ++qq) {
        int ph = (qq + swz) & 3;
        *(uint2*)(dst + ph * 4) = *(const uint2*)(outv + qq * 4);
      }
    } else {
      *(uint4*)dst = make_uint4(0u, 0u, 0u, 0u);
      *(uint4*)(dst + 8) = make_uint4(0u, 0u, 0u, 0u);
    }
  }
  __syncthreads();

  int w = t & 63, q = t >> 6;
  float wv[9][4];
#pragma unroll
  for (int j = 0; j < 4; ++j) {
    int hc = hc0 + q * 4 + j;
#pragma unroll
    for (int tap = 0; tap < 9; ++tap) wv[tap][j] = w_dw[hc * 9 + tap];
  }

  f32x4 win[3][3];
  float acc_s = 0.f, acc_ss = 0.f;

  auto ld4 = [&](int r, int dwi) -> f32x4 {
    int slot = w + dwi;
    int ph = (q + (slot >> 2)) & 3;
    const bf16* p = tile + (r * 66 + slot) * 16 + ph * 4;
    uint2 u = *(const uint2*)p;
    const bf16* pb = (const bf16*)&u;
    return (f32x4){bf2f(pb[0]), bf2f(pb[1]), bf2f(pb[2]), bf2f(pb[3])};
  };

#pragma unroll
  for (int dwi = 0; dwi < 3; ++dwi) {
    win[0][dwi] = ld4(0, dwi);
    win[1][dwi] = ld4(1, dwi);
  }
#pragma unroll
  for (int orow = 0; orow < 16; ++orow) {
    int rnew = orow + 2;
    int ringn = rnew % 3;
#pragma unroll
    for (int dwi = 0; dwi < 3; ++dwi) win[ringn][dwi] = ld4(rnew, dwi);
    f32x4 acc = (f32x4){0.f, 0.f, 0.f, 0.f};
#pragma unroll
    for (int dr = 0; dr < 3; ++dr) {
      int ring = (orow + dr) % 3;
#pragma unroll
      for (int dwi = 0; dwi < 3; ++dwi) {
#pragma unroll
        for (int j = 0; j < 4; ++j)
          acc[j] = fmaf(win[ring][dwi][j], wv[dr * 3 + dwi][j], acc[j]);
      }
    }
#pragma unroll
    for (int j = 0; j < 4; ++j) { acc_s += acc[j]; acc_ss += acc[j] * acc[j]; }
    if (!(orow & 1) && !(w & 1)) {
      int hglob = h0 + orow;
      int pos2 = (hglob >> 1) * 32 + (w >> 1);
      bf16 tmp[4];
#pragma unroll
      for (int j = 0; j < 4; ++j) tmp[j] = f2bf(acc[j]);
      *(uint2*)((char*)h2cl + ((size_t)(b * 1024 + pos2) * 512 + hc0 + q * 4) * 2) =
          *(const uint2*)tmp;
    }
  }

#pragma unroll
  for (int off = 32; off; off >>= 1) {
    acc_s += __shfl_down(acc_s, off, 64);
    acc_ss += __shfl_down(acc_ss, off, 64);
  }
  int wave = t >> 6;
  if ((t & 63) == 0) { red2[wave][0] = acc_s; red2[wave][1] = acc_ss; }
  __syncthreads();
  if (t < 2) {
    float v = red2[0][t] + red2[1][t] + red2[2][t] + red2[3][t];
    atomicAdd(&stats2[(b * 8 + hcb) * 2 + t], v);
  }
}

// ---------------- pw2 MFMA with fused GN2+SiLU on B staging ----------------
__global__ __launch_bounds__(256) void pw2_mfma(
    const bf16* __restrict__ h2raw, const bf16* __restrict__ wp2T,
    const float* __restrict__ st2, const float* __restrict__ gs2,
    const float* __restrict__ gb2, float* __restrict__ h3,
    float* __restrict__ stats3) {
  __shared__ __align__(16) char als[2][8192];
  __shared__ __align__(16) char bls[2][4096];
  __shared__ float red[4][8][2];
  int blk = blockIdx.x;
  int n0 = blk * 64;
  int b = n0 >> 10, posb = n0 & 1023;
  int t = threadIdx.x, lane = t & 63, wave = t >> 6;
  int quad = lane >> 4, l15 = lane & 15;
  int wbase = wave * 16;

  f32x4 acc[8];
#pragma unroll
  for (int mt = 0; mt < 8; ++mt) acc[mt] = (f32x4){0.f, 0.f, 0.f, 0.f};

  auto stageB = [&](int buf, int kc) {
    int c4 = t >> 6, r = t & 63;
    int hcb = (kc * 4 + c4) * 8;
    int g = hcb >> 6;
    float mean = st2[(b * 8 + g) * 2], rstd = st2[(b * 8 + g) * 2 + 1];
    uint4 raw = *(const uint4*)((const char*)h2raw + (size_t)(n0 + r) * 1024 + (kc * 4 + c4) * 16);
    const bf16* pv = (const bf16*)&raw;
    bf16 outv[8];
#pragma unroll
    for (int j = 0; j < 8; ++j) {
      float v = bf2f(pv[j]);
      v = (v - mean) * rstd * gs2[hcb + j] + gb2[hcb + j];
      outv[j] = f2bf(siluf(v));
    }
    *(uint4*)(bls[buf] + c4 * 1024 + r * 16) = *(const uint4*)outv;
  };

  {
#pragma unroll
    for (int i = 0; i < 2; ++i) {
      int id = t + 256 * i;
      int c4 = id >> 7, r = id & 127;
      *(uint4*)(als[0] + c4 * 2048 + r * 16) =
          *(const uint4*)((const char*)wp2T + (size_t)r * 1024 + c4 * 16);
    }
    stageB(0, 0);
  }
  for (int kc = 0; kc < 16; ++kc) {
    __syncthreads();
    if (kc + 1 < 16) {
      int nb = (kc + 1) & 1;
#pragma unroll
      for (int i = 0; i < 2; ++i) {
        int id = t + 256 * i;
        int c4 = id >> 7, r = id & 127;
        *(uint4*)(als[nb] + c4 * 2048 + r * 16) =
            *(const uint4*)((const char*)wp2T + (size_t)r * 1024 + ((kc + 1) * 4 + c4) * 16);
      }
      stageB(nb, kc + 1);
    }
    int buf = kc & 1;
    bf16x8 bf1 = *(const bf16x8*)(bls[buf] + quad * 1024 + (wbase + l15) * 16);
#pragma unroll
    for (int mt = 0; mt < 8; ++mt) {
      bf16x8 af = *(const bf16x8*)(als[buf] + quad * 2048 + (mt * 16 + l15) * 16);
      acc[mt] = __builtin_amdgcn_mfma_f32_16x16x32_bf16(af, bf1, acc[mt], 0, 0, 0);
    }
  }

#pragma unroll
  for (int mt = 0; mt < 8; ++mt) {
    float s = 0.f, ss = 0.f;
    int pos = posb + wbase + l15;
#pragma unroll
    for (int r = 0; r < 4; ++r) {
      float v = acc[mt][r];
      s += v;
      ss += v * v;
      int co = mt * 16 + quad * 4 + r;
      h3[(size_t)(b * 128 + co) * 1024 + pos] = v;
    }
#pragma unroll
    for (int off = 32; off; off >>= 1) {
      s += __shfl_down(s, off, 64);
      ss += __shfl_down(ss, off, 64);
    }
    if (lane == 0) { red[wave][mt][0] = s; red[wave][mt][1] = ss; }
  }
  __syncthreads();
  if (t < 16) {
    int mt = t >> 1, which = t & 1;
    float v = red[0][mt][which] + red[1][mt][which] + red[2][mt][which] + red[3][mt][which];
    atomicAdd(&stats3[(b * 8 + mt) * 2 + which], v);
  }
}

// ---------------- final GN+SiLU -> d_out (fp32) ----------------------------
__global__ void out_kernel(const float* __restrict__ h3, const float* __restrict__ stats,
                           const float* __restrict__ gs, const float* __restrict__ gb,
                           float* __restrict__ out) {
  const int total = B_ * COUT_ * 1024;
  for (int idx = blockIdx.x * blockDim.x + threadIdx.x; idx < total; idx += gridDim.x * blockDim.x) {
    int c = (idx >> 10) & 127;
    int b = idx >> 17;
    int bg = b * 8 + (c >> 4);
    float S = stats[bg * 2], SS = stats[bg * 2 + 1];
    float mean = S * (1.f / 16384.f);
    float var = SS * (1.f / 16384.f) - mean * mean;
    float rstd = rsqrtf(var + 1e-5f);
    float v = (h3[idx] - mean) * rstd * gs[c] + gb[c];
    out[idx] = siluf(v);
  }
}

extern "C" void kernel_launch(void* const* d_in, const int* in_sizes, int n_in,
                              void* d_out, int out_size, void* d_ws, size_t ws_size,
                              hipStream_t stream) {
  const float* x = (const float*)d_in[0];
  const float* w_exp = (const float*)d_in[1];
  const float* gn_exp_s = (const float*)d_in[2];
  const float* gn_exp_b = (const float*)d_in[3];
  const float* w1 = (const float*)d_in[4];
  const float* b1 = (const float*)d_in[5];
  const float* w2 = (const float*)d_in[6];
  const float* b2 = (const float*)d_in[7];
  const float* w_pw1 = (const float*)d_in[8];
  const float* gn1_s = (const float*)d_in[9];
  const float* gn1_b = (const float*)d_in[10];
  const float* w_dw = (const float*)d_in[11];
  const float* gn2_s = (const float*)d_in[12];
  const float* gn2_b = (const float*)d_in[13];
  const float* w_pw2 = (const float*)d_in[14];
  const float* gn3_s = (const float*)d_in[15];
  const float* gn3_b = (const float*)d_in[16];

  char* ws = (char*)d_ws;
  const size_t WP1T_OFF = 16384;
  const size_t WP2T_OFF = WP1T_OFF + 131072;
  const size_t XT_OFF = WP2T_OFF + 131072;                 // 278528
  const size_t WT_OFF = XT_OFF + 16777216;                 // 17055744
  const size_t YS_OFF = WT_OFF + 2359296;                  // 19415040
  const size_t NEEDED = YS_OFF + 134217728;                // 153632768
  if (ws_size < NEEDED) return;

  float* wts = (float*)ws;
  float* stats1 = (float*)(ws + 1024);
  float* stats2 = (float*)(ws + 2048);
  float* stats3 = (float*)(ws + 3072);
  float* statsE = (float*)(ws + 4096);
  bf16* wp1T = (bf16*)(ws + WP1T_OFF);
  bf16* wp2T = (bf16*)(ws + WP2T_OFF);
  bf16* xT = (bf16*)(ws + XT_OFF);
  bf16* ccl = (bf16*)(ws + XT_OFF);
  bf16* wT = (bf16*)(ws + WT_OFF);
  bf16* ys = (bf16*)(ws + YS_OFF);
  bf16* h1cl = (bf16*)(ws + YS_OFF);
  bf16* h2cl = (bf16*)(ws + YS_OFF + 67108864);
  float* h3 = (float*)(ws + YS_OFF + 83886080);

  hipMemsetAsync(ws, 0, 16384, stream);
  gate_kernel<<<1, 64, 0, stream>>>(w1, b1, w2, b2, wts);
  xt_kernel<<<B_ * 64, 256, 0, stream>>>(x, xT);
  wt_kernel<<<4608, 256, 0, stream>>>(w_exp, wT);
  wpT_kernel<<<512, 256, 0, stream>>>(w_pw1, w_pw2, wp1T, wp2T);
  conv_mfma<<<E_ * B_ * 32, 256, 0, stream>>>(xT, wT, statsE, ys);
  finalize_stats<<<4, 256, 0, stream>>>(statsE, 1024, 1.f / 65536.f);
  combine_cl<<<B_ * 64, 256, 0, stream>>>(x, ys, statsE, gn_exp_s, gn_exp_b, wts, ccl);
  pw1_mfma<<<4 * 512, 256, 0, stream>>>(ccl, wp1T, h1cl, stats1);
  finalize_stats<<<1, 128, 0, stream>>>(stats1, 128, 1.f / 262144.f);
  dw_cl<<<B_ * 32 * 4, 256, 0, stream>>>(h1cl, w_dw, stats1, gn1_s, gn1_b, h2cl, stats2);
  finalize_stats<<<1, 128, 0, stream>>>(stats2, 128, 1.f / 262144.f);
  pw2_mfma<<<256, 256, 0, stream>>>(h2cl, wp2T, stats2, gn2_s, gn2_b, h3, stats3);
  out_kernel<<<1024, 256, 0, stream>>>(h3, stats3, gn3_s, gn3_b, (float*)d_out);
}

// Round 9
// 540.281 us; speedup vs baseline: 1.0599x; 1.0217x over previous
//
#include <hip/hip_runtime.h>
#include <hip/hip_bf16.h>

// ---------------------------------------------------------------------------
// PCELayer R9.
//  conv_mfma v5 = R5's 4-row geometry (24 ds_read/64 MFMA -> LDS floor 69us
//  < MFMA floor 74.5us) + R8's W LDS-double-buffer DMA pipeline (16KB/tap
//  global_load_lds issued right after the tap barrier -> hidden behind the
//  1242-cyc MFMA window; ONE barrier/tap). LDS exactly 81920B (xls 48K +
//  wls 2x16K) -> 2 blocks/CU; GN stats via per-wave direct atomics (no red[]).
//  R8 lesson: 2-row geometry has 116us LDS-throughput floor + halved DMA
//  window + 2x X refetch -> pipeline must ride the 4-row tile.
//  Back half identical to R8 (pw2 fuses GN2+SiLU).
// Workspace (153.6 MB): head 16K | wp1T 128K | wp2T 128K | XT 16.8M | WT 2.4M
//   | YS 134.2M (-> h1cl 67M | h2cl 16.8M | h3 8.4M)
// ---------------------------------------------------------------------------

#define B_ 16
#define CIN_ 128
#define COUT_ 128
#define H_ 64
#define W_ 64
#define HW_ 4096
#define E_ 8
#define FF_ 8
#define GC_ 32
#define HID_ 64
#define HC_ 512

typedef __hip_bfloat16 bf16;
typedef __bf16 bf16x8 __attribute__((ext_vector_type(8)));
typedef float f32x4 __attribute__((ext_vector_type(4)));

__device__ __forceinline__ float siluf(float v) { return v / (1.f + __expf(-v)); }
__device__ __forceinline__ float bf2f(bf16 v) { return __bfloat162float(v); }
__device__ __forceinline__ bf16 f2bf(float v) { return __float2bfloat16(v); }

__device__ __forceinline__ void async_copy16(void* lds, const void* g) {
  __builtin_amdgcn_global_load_lds(
      (const __attribute__((address_space(1))) unsigned int*)g,
      (__attribute__((address_space(3))) unsigned int*)lds, 16, 0, 0);
}

// ---------------- router gate ----------------------------------------------
__global__ void gate_kernel(const float* __restrict__ w1, const float* __restrict__ b1,
                            const float* __restrict__ w2, const float* __restrict__ b2,
                            float* __restrict__ wts) {
  int p = threadIdx.x;
  if (p >= 16) return;
  int i = p >> 2, j = p & 3;
  float cy = (i + 0.5f) * 0.25f;
  float cx = (j + 0.5f) * 0.25f;
  float feats[GC_];
#pragma unroll
  for (int f = 0; f < FF_; ++f) {
    float fr = 3.14159265358979f * (float)(1 << f);
    float ay = cy * fr, ax = cx * fr;
    feats[f] = sinf(ay);
    feats[FF_ + f] = cosf(ay);
    feats[2 * FF_ + f] = sinf(ax);
    feats[3 * FF_ + f] = cosf(ax);
  }
  float hid[HID_];
  for (int k = 0; k < HID_; ++k) {
    float a = b1[k];
#pragma unroll
    for (int m = 0; m < GC_; ++m) a = fmaf(feats[m], w1[m * HID_ + k], a);
    hid[k] = siluf(a);
  }
  float lg[E_];
  float mx = -1e30f;
#pragma unroll
  for (int e = 0; e < E_; ++e) {
    float a = b2[e];
    for (int k = 0; k < HID_; ++k) a = fmaf(hid[k], w2[k * E_ + e], a);
    lg[e] = a;
    mx = fmaxf(mx, a);
  }
  float s = 0.f;
#pragma unroll
  for (int e = 0; e < E_; ++e) { lg[e] = __expf(lg[e] - mx); s += lg[e]; }
  float inv = 1.f / s;
#pragma unroll
  for (int e = 0; e < E_; ++e) wts[p * E_ + e] = lg[e] * inv;
}

// ---------------- x -> channels-last bf16 ----------------------------------
__global__ __launch_bounds__(256) void xt_kernel(const float* __restrict__ x,
                                                 bf16* __restrict__ xT) {
  __shared__ float t[128][65];
  int b = blockIdx.x >> 6, h = blockIdx.x & 63;
  int tid = threadIdx.x;
  int w = tid & 63, c4 = tid >> 6;
  const float* xb = x + ((size_t)(b * 128) * 64 + h) * 64;
#pragma unroll 4
  for (int rep = 0; rep < 32; ++rep) {
    int ci = rep * 4 + c4;
    t[ci][w] = xb[(size_t)ci * HW_ + w];
  }
  __syncthreads();
  bf16* dst = xT + (size_t)(b * 64 + h) * 8192;
#pragma unroll 4
  for (int rep = 0; rep < 32; ++rep) {
    int o = rep * 256 + tid;
    int cg = o >> 9, w2 = (o >> 3) & 63, lo = o & 7;
    dst[o] = f2bf(t[cg * 8 + lo][w2]);
  }
}

// ---------------- w_exp -> wT bf16 -----------------------------------------
__global__ void wt_kernel(const float* __restrict__ w_exp, bf16* __restrict__ wT) {
  int idx = blockIdx.x * 256 + threadIdx.x;
  if (idx >= 1179648) return;
  int lo = idx & 7;
  int co = (idx >> 3) & 127;
  int cg = (idx >> 10) & 15;
  int rest = idx >> 14;
  int tap = rest % 9, e = rest / 9;
  int ci = cg * 8 + lo;
  wT[idx] = f2bf(w_exp[(((size_t)(e * 128 + co) * 128 + ci) * 9) + tap]);
}

// ---------------- pw weights fp32 -> bf16 ----------------------------------
__global__ void wpT_kernel(const float* __restrict__ w_pw1, const float* __restrict__ w_pw2,
                           bf16* __restrict__ wp1T, bf16* __restrict__ wp2T) {
  int idx = blockIdx.x * 256 + threadIdx.x;
  if (idx < 65536) wp1T[idx] = f2bf(w_pw1[idx]);
  else if (idx < 131072) wp2T[idx - 65536] = f2bf(w_pw2[idx - 65536]);
}

// ---------------- expert conv via MFMA (v5: 4-row + W LDS-dbuf DMA) --------
// grid: e(8) x b(16) x rt(16 tiles of 4 rows). 256 thr = 4 waves.
// Block: 128co x 256pos. Wave: row h_local=wave, 8mt x 4nt of 16x16x32.
// kt = half*9+tap in 0..17; W in wls[kt&1]; next tap's W DMA'd right after
// this tap's barrier into wls[(kt+1)&1] (one barrier per tap).
__global__ __launch_bounds__(256, 2) void conv_mfma(
    const bf16* __restrict__ xT, const bf16* __restrict__ wT,
    float* __restrict__ statsE, bf16* __restrict__ ys) {
  __shared__ __align__(16) char xls[8 * 6144];     // [cg(8)][r(6)][w(64)]x16B = 48K
  __shared__ __align__(16) char wls[2][16384];     // [cg(8)][co(128)]x16B each
  // total LDS = 81920 B exactly -> 2 blocks/CU

  int blk = blockIdx.x;
  int rt = blk & 15, b = (blk >> 4) & 15, e = blk >> 8;
  int tid = threadIdx.x, lane = tid & 63, wave = tid >> 6;
  int quad = lane >> 4, l15 = lane & 15;
  int h0 = rt * 4;
  int h_local = wave;

  f32x4 acc[8][4];
#pragma unroll
  for (int mt = 0; mt < 8; ++mt)
#pragma unroll
    for (int nt = 0; nt < 4; ++nt) acc[mt][nt] = (f32x4){0.f, 0.f, 0.f, 0.f};

  bf16x8 bz;
#pragma unroll
  for (int j = 0; j < 8; ++j) bz[j] = (__bf16)0.f;

  // W DMA: one tap's 16KB into wls[buf]; 4 segs of 1KB per wave.
  auto wdma = [&](int kt2, int buf) {
    int hf = kt2 / 9, tp = kt2 - hf * 9;
#pragma unroll
    for (int s = 0; s < 4; ++s) {
      int seg = wave * 4 + s;
      int cg = seg >> 1, cb = seg & 1;
      const char* g = (const char*)wT +
          (size_t)(((e * 9 + tp) * 16) + hf * 8 + cg) * 2048 + cb * 1024 + lane * 16;
      async_copy16(wls[buf] + cg * 2048 + cb * 1024 + lane * 16, g);
    }
  };
  // X stage (vector loads): one ci-half's 48KB (8cg x 6r); 12 segs per wave.
  auto xstage = [&](int half) {
#pragma unroll
    for (int s = 0; s < 12; ++s) {
      int seg = wave * 12 + s;
      int cg = seg / 6, r = seg % 6;
      int h = h0 - 1 + r;
      char* ldst = xls + cg * 6144 + r * 1024 + lane * 16;
      if ((unsigned)h < 64u) {
        const uint4* g = (const uint4*)((const char*)xT +
            ((size_t)((b * 64 + h) * 16) + half * 8 + cg) * 1024) + lane;
        *(uint4*)ldst = *g;
      } else {
        *(uint4*)ldst = make_uint4(0u, 0u, 0u, 0u);
      }
    }
  };

  wdma(0, 0);
  xstage(0);

  for (int kt = 0; kt < 18; ++kt) {
    if (kt == 9) {
      __syncthreads();  // all half-0 xls readers done
      xstage(1);        // (W for tap 9 already in flight from kt=8's wdma)
    }
    __syncthreads();    // publish X writes + drain W DMA (in flight a full tap)
    if (kt + 1 < 18) wdma(kt + 1, (kt + 1) & 1);  // flies during this tap's MFMA
    int tap = kt % 9;
    int dr = tap / 3, ds = tap % 3;
    int r_local = h_local + dr;
    const char* wb = wls[kt & 1];
#pragma unroll
    for (int kc = 0; kc < 2; ++kc) {
      int cgq = kc * 4 + quad;
      bf16x8 af[8];
#pragma unroll
      for (int mt = 0; mt < 8; ++mt)
        af[mt] = *(const bf16x8*)(wb + cgq * 2048 + (mt * 16 + l15) * 16);
      bf16x8 bfr[4];
#pragma unroll
      for (int nt = 0; nt < 4; ++nt) {
        int w = nt * 16 + l15;
        int wsrc = w + ds - 1;
        bool valid = (unsigned)wsrc < 64u;
        int wc = valid ? wsrc : 0;
        bf16x8 v = *(const bf16x8*)(xls + cgq * 6144 + (r_local * 64 + wc) * 16);
        bfr[nt] = valid ? v : bz;
      }
#pragma unroll
      for (int mt = 0; mt < 8; ++mt)
#pragma unroll
        for (int nt = 0; nt < 4; ++nt)
          acc[mt][nt] = __builtin_amdgcn_mfma_f32_16x16x32_bf16(
              af[mt], bfr[nt], acc[mt][nt], 0, 0, 0);
    }
  }

  // epilogue: raw ys + GN partial stats (group g = mt), per-wave atomics
  int hh = h0 + h_local;
  bf16* yb = ys + (size_t)((e * 16 + b) * 128) * 4096;
#pragma unroll
  for (int mt = 0; mt < 8; ++mt) {
    float s = 0.f, ss = 0.f;
#pragma unroll
    for (int nt = 0; nt < 4; ++nt) {
      int w = nt * 16 + l15;
      int pos = hh * 64 + w;
#pragma unroll
      for (int r = 0; r < 4; ++r) {
        float v = acc[mt][nt][r];
        s += v;
        ss += v * v;
        int co = mt * 16 + quad * 4 + r;
        yb[(size_t)co * 4096 + pos] = f2bf(v);
      }
    }
#pragma unroll
    for (int off = 32; off; off >>= 1) {
      s += __shfl_down(s, off, 64);
      ss += __shfl_down(ss, off, 64);
    }
    if (lane == 0) {
      atomicAdd(&statsE[((e * 16 + b) * 8 + mt) * 2], s);
      atomicAdd(&statsE[((e * 16 + b) * 8 + mt) * 2 + 1], ss);
    }
  }
}

// ---------------- generic stats finalize: raw S/SS -> mean/rstd ------------
__global__ void finalize_stats(float* __restrict__ st, int n, float inv) {
  int i = blockIdx.x * 256 + threadIdx.x;
  if (i >= n) return;
  float S = st[i * 2], SS = st[i * 2 + 1];
  float mean = S * inv;
  float var = SS * inv - mean * mean;
  st[i * 2] = mean;
  st[i * 2 + 1] = rsqrtf(var + 1e-5f);
}

// ---------------- combine -> bf16 channels-last ----------------------------
__global__ __launch_bounds__(256) void combine_cl(
    const float* __restrict__ x, const bf16* __restrict__ ys,
    const float* __restrict__ st, const float* __restrict__ gns,
    const float* __restrict__ gnb, const float* __restrict__ wts,
    bf16* __restrict__ ccl) {
  __shared__ bf16 tile[64][132];
  int b = blockIdx.x >> 6, h = blockIdx.x & 63;
  int t = threadIdx.x;
  int w32 = t & 31, coq = t >> 5;
  float m_[8], r_[8];
#pragma unroll
  for (int e = 0; e < 8; ++e) {
    m_[e] = st[((e * 16 + b) * 8 + coq) * 2];
    r_[e] = st[((e * 16 + b) * 8 + coq) * 2 + 1];
  }
#pragma unroll
  for (int wt2 = 0; wt2 < 2; ++wt2) {
    int w = wt2 * 32 + w32;
    int pid = (h >> 4) * 4 + (w >> 4);
    int pos = h * 64 + w;
    float wt_[8];
#pragma unroll
    for (int e = 0; e < 8; ++e) wt_[e] = wts[pid * 8 + e];
    for (int coi = 0; coi < 16; ++coi) {
      int co = coq * 16 + coi;
      float v = x[((size_t)(b * 128 + co) << 12) + pos];
#pragma unroll
      for (int e = 0; e < 8; ++e) {
        float y = bf2f(ys[((size_t)((e * 16 + b) * 128 + co) << 12) + pos]);
        float yn = (y - m_[e]) * r_[e] * gns[e * 128 + co] + gnb[e * 128 + co];
        v += siluf(yn) * wt_[e];
      }
      tile[w][co] = f2bf(v);
    }
  }
  __syncthreads();
  int row = t >> 2, q = t & 3;
  char* dst = (char*)ccl + ((size_t)(b * 4096 + h * 64 + row)) * 256 + q * 64;
  const char* src = (const char*)&tile[row][0] + q * 64;
#pragma unroll
  for (int i = 0; i < 4; ++i)
    *(uint4*)(dst + i * 16) = *(const uint4*)(src + i * 16);
}

// ---------------- pw1 MFMA: h1[hc=512][n=65536] = w[hc][ci] @ ccl[n][ci] ---
__global__ __launch_bounds__(256) void pw1_mfma(
    const bf16* __restrict__ ccl, const bf16* __restrict__ wp1T,
    bf16* __restrict__ h1cl, float* __restrict__ stats1) {
  __shared__ __align__(16) char ls[65536];  // als 32K | bls 32K ; reused as tile
  __shared__ float red[4][2][2];
  char* als = ls;
  char* bls = ls + 32768;
  int blk = blockIdx.x;
  int ntile = blk & 511, mtile = blk >> 9;
  int n0 = ntile * 128, m0 = mtile * 128;
  int t = threadIdx.x, lane = t & 63, wave = t >> 6;
  int quad = lane >> 4, l15 = lane & 15;
  int b = n0 >> 12;

#pragma unroll
  for (int i = 0; i < 8; ++i) {
    int id = t + 256 * i;
    int r = id >> 4, c = id & 15;
    *(uint4*)(als + c * 2048 + r * 16) =
        *(const uint4*)((const char*)wp1T + (size_t)(m0 + r) * 256 + c * 16);
    *(uint4*)(bls + c * 2048 + r * 16) =
        *(const uint4*)((const char*)ccl + (size_t)(n0 + r) * 256 + c * 16);
  }
  __syncthreads();

  f32x4 acc[8][2];
#pragma unroll
  for (int mt = 0; mt < 8; ++mt)
#pragma unroll
    for (int nt = 0; nt < 2; ++nt) acc[mt][nt] = (f32x4){0.f, 0.f, 0.f, 0.f};

#pragma unroll
  for (int kc = 0; kc < 4; ++kc) {
    int cgq = kc * 4 + quad;
    bf16x8 af[8];
#pragma unroll
    for (int mt = 0; mt < 8; ++mt)
      af[mt] = *(const bf16x8*)(als + cgq * 2048 + (mt * 16 + l15) * 16);
    bf16x8 bfr[2];
#pragma unroll
    for (int nt = 0; nt < 2; ++nt)
      bfr[nt] = *(const bf16x8*)(bls + cgq * 2048 + (wave * 32 + nt * 16 + l15) * 16);
#pragma unroll
    for (int mt = 0; mt < 8; ++mt)
#pragma unroll
      for (int nt = 0; nt < 2; ++nt)
        acc[mt][nt] = __builtin_amdgcn_mfma_f32_16x16x32_bf16(
            af[mt], bfr[nt], acc[mt][nt], 0, 0, 0);
  }

  __syncthreads();  // everyone done with als/bls
  float s[2] = {0.f, 0.f}, ss[2] = {0.f, 0.f};
  bf16* tile = (bf16*)ls;  // row stride 132 elems = 264 B
#pragma unroll
  for (int mt = 0; mt < 8; ++mt) {
    int gi = mt >> 2;
#pragma unroll
    for (int nt = 0; nt < 2; ++nt) {
      int n = wave * 32 + nt * 16 + l15;
#pragma unroll
      for (int r = 0; r < 4; ++r) {
        float v = acc[mt][nt][r];
        s[gi] += v;
        ss[gi] += v * v;
        tile[n * 132 + mt * 16 + quad * 4 + r] = f2bf(v);
      }
    }
  }
#pragma unroll
  for (int gi = 0; gi < 2; ++gi) {
#pragma unroll
    for (int off = 32; off; off >>= 1) {
      s[gi] += __shfl_down(s[gi], off, 64);
      ss[gi] += __shfl_down(ss[gi], off, 64);
    }
  }
  if (lane == 0) {
    red[wave][0][0] = s[0]; red[wave][0][1] = ss[0];
    red[wave][1][0] = s[1]; red[wave][1][1] = ss[1];
  }
  __syncthreads();
  if (t < 4) {
    int gi = t >> 1, which = t & 1;
    float v = red[0][gi][which] + red[1][gi][which] + red[2][gi][which] + red[3][gi][which];
    atomicAdd(&stats1[(b * 8 + mtile * 2 + gi) * 2 + which], v);
  }
#pragma unroll
  for (int i = 0; i < 8; ++i) {
    int id = t + 256 * i;             // 0..2047
    int r = id >> 4, q = id & 15;     // 128 rows x 16 chunks of 16B
    char* dst = (char*)h1cl + (size_t)(n0 + r) * 1024 + m0 * 2 + q * 16;
    const char* src = (const char*)tile + r * 264 + q * 16;
    *(uint4*)dst = *(const uint4*)src;
  }
}

// ---------------- dw3x3 v2: LDS-staged GN1+SiLU tile + sliding stencil -----
__global__ __launch_bounds__(256) void dw_cl(
    const bf16* __restrict__ h1cl, const float* __restrict__ w_dw,
    const float* __restrict__ st1, const float* __restrict__ gs,
    const float* __restrict__ gb, bf16* __restrict__ h2cl,
    float* __restrict__ stats2) {
  __shared__ __align__(16) bf16 tile[18 * 66 * 16];  // 38016 B
  __shared__ float red2[4][2];
  int blk = blockIdx.x;
  int ht = blk & 3, hcg = (blk >> 2) & 31, b = blk >> 7;
  int h0 = ht * 16;
  int hc0 = hcg * 16;
  int hcb = hcg >> 2;  // 64-hc GN group
  int t = threadIdx.x;

  float mean = st1[(b * 8 + hcb) * 2], rstd = st1[(b * 8 + hcb) * 2 + 1];
  float scale[16], shift[16];
#pragma unroll
  for (int j = 0; j < 16; ++j) {
    float g = gs[hc0 + j];
    scale[j] = rstd * g;
    shift[j] = gb[hc0 + j] - mean * rstd * g;
  }

  for (int i = 0; i < 5; ++i) {
    int idx = t + 256 * i;
    if (idx >= 1188) break;
    int row = idx / 66, wslot = idx - row * 66;
    int hh = h0 - 1 + row;
    int w = wslot - 1;
    int swz = (wslot >> 2) & 3;
    bf16* dst = tile + (row * 66 + wslot) * 16;
    if ((unsigned)hh < 64u && (unsigned)w < 64u) {
      const char* p = (const char*)h1cl + ((size_t)(b * 4096 + hh * 64 + w) * 512 + hc0) * 2;
      uint4 a0 = *(const uint4*)p;
      uint4 a1 = *(const uint4*)(p + 16);
      const bf16* pv = (const bf16*)&a0;
      const bf16* pv1 = (const bf16*)&a1;
      bf16 outv[16];
#pragma unroll
      for (int j = 0; j < 8; ++j)
        outv[j] = f2bf(siluf(bf2f(pv[j]) * scale[j] + shift[j]));
#pragma unroll
      for (int j = 0; j < 8; ++j)
        outv[8 + j] = f2bf(siluf(bf2f(pv1[j]) * scale[8 + j] + shift[8 + j]));
#pragma unroll
      for (int qq = 0; qq < 4; ++qq) {
        int ph = (qq + swz) & 3;
        *(uint2*)(dst + ph * 4) = *(const uint2*)(outv + qq * 4);
      }
    } else {
      *(uint4*)dst = make_uint4(0u, 0u, 0u, 0u);
      *(uint4*)(dst + 8) = make_uint4(0u, 0u, 0u, 0u);
    }
  }
  __syncthreads();

  int w = t & 63, q = t >> 6;
  float wv[9][4];
#pragma unroll
  for (int j = 0; j < 4; ++j) {
    int hc = hc0 + q * 4 + j;
#pragma unroll
    for (int tap = 0; tap < 9; ++tap) wv[tap][j] = w_dw[hc * 9 + tap];
  }

  f32x4 win[3][3];
  float acc_s = 0.f, acc_ss = 0.f;

  auto ld4 = [&](int r, int dwi) -> f32x4 {
    int slot = w + dwi;
    int ph = (q + (slot >> 2)) & 3;
    const bf16* p = tile + (r * 66 + slot) * 16 + ph * 4;
    uint2 u = *(const uint2*)p;
    const bf16* pb = (const bf16*)&u;
    return (f32x4){bf2f(pb[0]), bf2f(pb[1]), bf2f(pb[2]), bf2f(pb[3])};
  };

#pragma unroll
  for (int dwi = 0; dwi < 3; ++dwi) {
    win[0][dwi] = ld4(0, dwi);
    win[1][dwi] = ld4(1, dwi);
  }
#pragma unroll
  for (int orow = 0; orow < 16; ++orow) {
    int rnew = orow + 2;
    int ringn = rnew % 3;
#pragma unroll
    for (int dwi = 0; dwi < 3; ++dwi) win[ringn][dwi] = ld4(rnew, dwi);
    f32x4 acc = (f32x4){0.f, 0.f, 0.f, 0.f};
#pragma unroll
    for (int dr = 0; dr < 3; ++dr) {
      int ring = (orow + dr) % 3;
#pragma unroll
      for (int dwi = 0; dwi < 3; ++dwi) {
#pragma unroll
        for (int j = 0; j < 4; ++j)
          acc[j] = fmaf(win[ring][dwi][j], wv[dr * 3 + dwi][j], acc[j]);
      }
    }
#pragma unroll
    for (int j = 0; j < 4; ++j) { acc_s += acc[j]; acc_ss += acc[j] * acc[j]; }
    if (!(orow & 1) && !(w & 1)) {
      int hglob = h0 + orow;
      int pos2 = (hglob >> 1) * 32 + (w >> 1);
      bf16 tmp[4];
#pragma unroll
      for (int j = 0; j < 4; ++j) tmp[j] = f2bf(acc[j]);
      *(uint2*)((char*)h2cl + ((size_t)(b * 1024 + pos2) * 512 + hc0 + q * 4) * 2) =
          *(const uint2*)tmp;
    }
  }

#pragma unroll
  for (int off = 32; off; off >>= 1) {
    acc_s += __shfl_down(acc_s, off, 64);
    acc_ss += __shfl_down(acc_ss, off, 64);
  }
  int wave = t >> 6;
  if ((t & 63) == 0) { red2[wave][0] = acc_s; red2[wave][1] = acc_ss; }
  __syncthreads();
  if (t < 2) {
    float v = red2[0][t] + red2[1][t] + red2[2][t] + red2[3][t];
    atomicAdd(&stats2[(b * 8 + hcb) * 2 + t], v);
  }
}

// ---------------- pw2 MFMA with fused GN2+SiLU on B staging ----------------
__global__ __launch_bounds__(256) void pw2_mfma(
    const bf16* __restrict__ h2raw, const bf16* __restrict__ wp2T,
    const float* __restrict__ st2, const float* __restrict__ gs2,
    const float* __restrict__ gb2, float* __restrict__ h3,
    float* __restrict__ stats3) {
  __shared__ __align__(16) char als[2][8192];
  __shared__ __align__(16) char bls[2][4096];
  __shared__ float red[4][8][2];
  int blk = blockIdx.x;
  int n0 = blk * 64;
  int b = n0 >> 10, posb = n0 & 1023;
  int t = threadIdx.x, lane = t & 63, wave = t >> 6;
  int quad = lane >> 4, l15 = lane & 15;
  int wbase = wave * 16;

  f32x4 acc[8];
#pragma unroll
  for (int mt = 0; mt < 8; ++mt) acc[mt] = (f32x4){0.f, 0.f, 0.f, 0.f};

  auto stageB = [&](int buf, int kc) {
    int c4 = t >> 6, r = t & 63;
    int hcb = (kc * 4 + c4) * 8;
    int g = hcb >> 6;
    float mean = st2[(b * 8 + g) * 2], rstd = st2[(b * 8 + g) * 2 + 1];
    uint4 raw = *(const uint4*)((const char*)h2raw + (size_t)(n0 + r) * 1024 + (kc * 4 + c4) * 16);
    const bf16* pv = (const bf16*)&raw;
    bf16 outv[8];
#pragma unroll
    for (int j = 0; j < 8; ++j) {
      float v = bf2f(pv[j]);
      v = (v - mean) * rstd * gs2[hcb + j] + gb2[hcb + j];
      outv[j] = f2bf(siluf(v));
    }
    *(uint4*)(bls[buf] + c4 * 1024 + r * 16) = *(const uint4*)outv;
  };

  {
#pragma unroll
    for (int i = 0; i < 2; ++i) {
      int id = t + 256 * i;
      int c4 = id >> 7, r = id & 127;
      *(uint4*)(als[0] + c4 * 2048 + r * 16) =
          *(const uint4*)((const char*)wp2T + (size_t)r * 1024 + c4 * 16);
    }
    stageB(0, 0);
  }
  for (int kc = 0; kc < 16; ++kc) {
    __syncthreads();
    if (kc + 1 < 16) {
      int nb = (kc + 1) & 1;
#pragma unroll
      for (int i = 0; i < 2; ++i) {
        int id = t + 256 * i;
        int c4 = id >> 7, r = id & 127;
        *(uint4*)(als[nb] + c4 * 2048 + r * 16) =
            *(const uint4*)((const char*)wp2T + (size_t)r * 1024 + ((kc + 1) * 4 + c4) * 16);
      }
      stageB(nb, kc + 1);
    }
    int buf = kc & 1;
    bf16x8 bf1 = *(const bf16x8*)(bls[buf] + quad * 1024 + (wbase + l15) * 16);
#pragma unroll
    for (int mt = 0; mt < 8; ++mt) {
      bf16x8 af = *(const bf16x8*)(als[buf] + quad * 2048 + (mt * 16 + l15) * 16);
      acc[mt] = __builtin_amdgcn_mfma_f32_16x16x32_bf16(af, bf1, acc[mt], 0, 0, 0);
    }
  }

#pragma unroll
  for (int mt = 0; mt < 8; ++mt) {
    float s = 0.f, ss = 0.f;
    int pos = posb + wbase + l15;
#pragma unroll
    for (int r = 0; r < 4; ++r) {
      float v = acc[mt][r];
      s += v;
      ss += v * v;
      int co = mt * 16 + quad * 4 + r;
      h3[(size_t)(b * 128 + co) * 1024 + pos] = v;
    }
#pragma unroll
    for (int off = 32; off; off >>= 1) {
      s += __shfl_down(s, off, 64);
      ss += __shfl_down(ss, off, 64);
    }
    if (lane == 0) { red[wave][mt][0] = s; red[wave][mt][1] = ss; }
  }
  __syncthreads();
  if (t < 16) {
    int mt = t >> 1, which = t & 1;
    float v = red[0][mt][which] + red[1][mt][which] + red[2][mt][which] + red[3][mt][which];
    atomicAdd(&stats3[(b * 8 + mt) * 2 + which], v);
  }
}

// ---------------- final GN+SiLU -> d_out (fp32) ----------------------------
__global__ void out_kernel(const float* __restrict__ h3, const float* __restrict__ stats,
                           const float* __restrict__ gs, const float* __restrict__ gb,
                           float* __restrict__ out) {
  const int total = B_ * COUT_ * 1024;
  for (int idx = blockIdx.x * blockDim.x + threadIdx.x; idx < total; idx += gridDim.x * blockDim.x) {
    int c = (idx >> 10) & 127;
    int b = idx >> 17;
    int bg = b * 8 + (c >> 4);
    float S = stats[bg * 2], SS = stats[bg * 2 + 1];
    float mean = S * (1.f / 16384.f);
    float var = SS * (1.f / 16384.f) - mean * mean;
    float rstd = rsqrtf(var + 1e-5f);
    float v = (h3[idx] - mean) * rstd * gs[c] + gb[c];
    out[idx] = siluf(v);
  }
}

extern "C" void kernel_launch(void* const* d_in, const int* in_sizes, int n_in,
                              void* d_out, int out_size, void* d_ws, size_t ws_size,
                              hipStream_t stream) {
  const float* x = (const float*)d_in[0];
  const float* w_exp = (const float*)d_in[1];
  const float* gn_exp_s = (const float*)d_in[2];
  const float* gn_exp_b = (const float*)d_in[3];
  const float* w1 = (const float*)d_in[4];
  const float* b1 = (const float*)d_in[5];
  const float* w2 = (const float*)d_in[6];
  const float* b2 = (const float*)d_in[7];
  const float* w_pw1 = (const float*)d_in[8];
  const float* gn1_s = (const float*)d_in[9];
  const float* gn1_b = (const float*)d_in[10];
  const float* w_dw = (const float*)d_in[11];
  const float* gn2_s = (const float*)d_in[12];
  const float* gn2_b = (const float*)d_in[13];
  const float* w_pw2 = (const float*)d_in[14];
  const float* gn3_s = (const float*)d_in[15];
  const float* gn3_b = (const float*)d_in[16];

  char* ws = (char*)d_ws;
  const size_t WP1T_OFF = 16384;
  const size_t WP2T_OFF = WP1T_OFF + 131072;
  const size_t XT_OFF = WP2T_OFF + 131072;                 // 278528
  const size_t WT_OFF = XT_OFF + 16777216;                 // 17055744
  const size_t YS_OFF = WT_OFF + 2359296;                  // 19415040
  const size_t NEEDED = YS_OFF + 134217728;                // 153632768
  if (ws_size < NEEDED) return;

  float* wts = (float*)ws;
  float* stats1 = (float*)(ws + 1024);
  float* stats2 = (float*)(ws + 2048);
  float* stats3 = (float*)(ws + 3072);
  float* statsE = (float*)(ws + 4096);
  bf16* wp1T = (bf16*)(ws + WP1T_OFF);
  bf16* wp2T = (bf16*)(ws + WP2T_OFF);
  bf16* xT = (bf16*)(ws + XT_OFF);
  bf16* ccl = (bf16*)(ws + XT_OFF);
  bf16* wT = (bf16*)(ws + WT_OFF);
  bf16* ys = (bf16*)(ws + YS_OFF);
  bf16* h1cl = (bf16*)(ws + YS_OFF);
  bf16* h2cl = (bf16*)(ws + YS_OFF + 67108864);
  float* h3 = (float*)(ws + YS_OFF + 83886080);

  hipMemsetAsync(ws, 0, 16384, stream);
  gate_kernel<<<1, 64, 0, stream>>>(w1, b1, w2, b2, wts);
  xt_kernel<<<B_ * 64, 256, 0, stream>>>(x, xT);
  wt_kernel<<<4608, 256, 0, stream>>>(w_exp, wT);
  wpT_kernel<<<512, 256, 0, stream>>>(w_pw1, w_pw2, wp1T, wp2T);
  conv_mfma<<<E_ * B_ * 16, 256, 0, stream>>>(xT, wT, statsE, ys);
  finalize_stats<<<4, 256, 0, stream>>>(statsE, 1024, 1.f / 65536.f);
  combine_cl<<<B_ * 64, 256, 0, stream>>>(x, ys, statsE, gn_exp_s, gn_exp_b, wts, ccl);
  pw1_mfma<<<4 * 512, 256, 0, stream>>>(ccl, wp1T, h1cl, stats1);
  finalize_stats<<<1, 128, 0, stream>>>(stats1, 128, 1.f / 262144.f);
  dw_cl<<<B_ * 32 * 4, 256, 0, stream>>>(h1cl, w_dw, stats1, gn1_s, gn1_b, h2cl, stats2);
  finalize_stats<<<1, 128, 0, stream>>>(stats2, 128, 1.f / 262144.f);
  pw2_mfma<<<256, 256, 0, stream>>>(h2cl, wp2T, stats2, gn2_s, gn2_b, h3, stats3);
  out_kernel<<<1024, 256, 0, stream>>>(h3, stats3, gn3_s, gn3_b, (float*)d_out);
}

// Round 10
// 498.284 us; speedup vs baseline: 1.1493x; 1.0843x over previous
//
#include <hip/hip_runtime.h>
#include <hip/hip_bf16.h>

// ---------------------------------------------------------------------------
// PCELayer R10.
//  conv_mfma: byte-exact R5 revert (167us known-good; R6-R9 pipeline attempts
//    all regressed - structure is at its plateau, MfmaUtil 41%).
//  Launch-count attack: prep kernel merges xt + gate + wpT + wT + stats
//    zeroing (5 launches -> 1); finalize_stats deleted (consumers compute
//    mean/rstd from raw S/SS inline). 14 dispatches -> 7.
//  combine_cl v2: vectorized uint4 ys reads (8 bf16/load, 32 loads/thread)
//    instead of 256 scalar bf16 loads; same LDS-bounce coalesced store.
// Workspace (153.6 MB): head 16K | wp1T 128K | wp2T 128K | XT 16.8M | WT 2.4M
//   | YS 134.2M (-> h1cl 67M | h2cl 16.8M | h3 8.4M)
// ---------------------------------------------------------------------------

#define B_ 16
#define CIN_ 128
#define COUT_ 128
#define H_ 64
#define W_ 64
#define HW_ 4096
#define E_ 8
#define FF_ 8
#define GC_ 32
#define HID_ 64
#define HC_ 512

typedef __hip_bfloat16 bf16;
typedef __bf16 bf16x8 __attribute__((ext_vector_type(8)));
typedef float f32x4 __attribute__((ext_vector_type(4)));

__device__ __forceinline__ float siluf(float v) { return v / (1.f + __expf(-v)); }
__device__ __forceinline__ float bf2f(bf16 v) { return __bfloat162float(v); }
__device__ __forceinline__ bf16 f2bf(float v) { return __float2bfloat16(v); }

// ---------------- prep: xt (0..1023) | gate+zero (1024) | wpT | wT ---------
__global__ __launch_bounds__(256) void prep_kernel(
    const float* __restrict__ x, const float* __restrict__ w1,
    const float* __restrict__ b1, const float* __restrict__ w2,
    const float* __restrict__ b2, const float* __restrict__ w_exp,
    const float* __restrict__ w_pw1, const float* __restrict__ w_pw2,
    bf16* __restrict__ xT, float* __restrict__ wts, char* __restrict__ zero_base,
    bf16* __restrict__ wp1T, bf16* __restrict__ wp2T, bf16* __restrict__ wT) {
  __shared__ float t[128][65];
  int blk = blockIdx.x;
  int tid = threadIdx.x;
  if (blk < 1024) {
    // ---- x -> channels-last bf16 ----
    int b = blk >> 6, h = blk & 63;
    int w = tid & 63, c4 = tid >> 6;
    const float* xb = x + ((size_t)(b * 128) * 64 + h) * 64;
#pragma unroll 4
    for (int rep = 0; rep < 32; ++rep) {
      int ci = rep * 4 + c4;
      t[ci][w] = xb[(size_t)ci * HW_ + w];
    }
    __syncthreads();
    bf16* dst = xT + (size_t)(b * 64 + h) * 8192;
#pragma unroll 4
    for (int rep = 0; rep < 32; ++rep) {
      int o = rep * 256 + tid;
      int cg = o >> 9, w2 = (o >> 3) & 63, lo = o & 7;
      dst[o] = f2bf(t[cg * 8 + lo][w2]);
    }
  } else if (blk == 1024) {
    // ---- zero stats region [1024,16384) + router gate ----
#pragma unroll
    for (int i = 0; i < 4; ++i) {
      int idx = i * 256 + tid;
      if (idx < 960)
        *(uint4*)(zero_base + 1024 + idx * 16) = make_uint4(0u, 0u, 0u, 0u);
    }
    int p = tid;
    if (p < 16) {
      int i = p >> 2, j = p & 3;
      float cy = (i + 0.5f) * 0.25f;
      float cx = (j + 0.5f) * 0.25f;
      float feats[GC_];
#pragma unroll
      for (int f = 0; f < FF_; ++f) {
        float fr = 3.14159265358979f * (float)(1 << f);
        float ay = cy * fr, ax = cx * fr;
        feats[f] = sinf(ay);
        feats[FF_ + f] = cosf(ay);
        feats[2 * FF_ + f] = sinf(ax);
        feats[3 * FF_ + f] = cosf(ax);
      }
      float hid[HID_];
      for (int k = 0; k < HID_; ++k) {
        float a = b1[k];
#pragma unroll
        for (int m = 0; m < GC_; ++m) a = fmaf(feats[m], w1[m * HID_ + k], a);
        hid[k] = siluf(a);
      }
      float lg[E_];
      float mx = -1e30f;
#pragma unroll
      for (int e = 0; e < E_; ++e) {
        float a = b2[e];
        for (int k = 0; k < HID_; ++k) a = fmaf(hid[k], w2[k * E_ + e], a);
        lg[e] = a;
        mx = fmaxf(mx, a);
      }
      float s = 0.f;
#pragma unroll
      for (int e = 0; e < E_; ++e) { lg[e] = __expf(lg[e] - mx); s += lg[e]; }
      float inv = 1.f / s;
#pragma unroll
      for (int e = 0; e < E_; ++e) wts[p * E_ + e] = lg[e] * inv;
    }
  } else if (blk < 1537) {
    // ---- pw weights fp32 -> bf16 (512 blocks) ----
    int idx = (blk - 1025) * 256 + tid;
    if (idx < 65536) wp1T[idx] = f2bf(w_pw1[idx]);
    else wp2T[idx - 65536] = f2bf(w_pw2[idx - 65536]);
  } else {
    // ---- w_exp -> wT bf16 (4608 blocks) ----
    int idx = (blk - 1537) * 256 + tid;
    if (idx < 1179648) {
      int lo = idx & 7;
      int co = (idx >> 3) & 127;
      int cg = (idx >> 10) & 15;
      int rest = idx >> 14;
      int tap = rest % 9, e = rest / 9;
      int ci = cg * 8 + lo;
      wT[idx] = f2bf(w_exp[(((size_t)(e * 128 + co) * 128 + ci) * 9) + tap]);
    }
  }
}

// ---------------- expert conv via MFMA (exact R5: 167us) -------------------
// grid: e(8) x b(16) x rt(16). 256 thr = 4 waves. Block: 128co x 256pos
// (4 rows x 64 w). Wave owns row h_local=wave, 8 mt x 4 nt.
__global__ __launch_bounds__(256, 2) void conv_mfma(
    const bf16* __restrict__ xT, const bf16* __restrict__ wT,
    float* __restrict__ statsE, bf16* __restrict__ ys) {
  __shared__ __align__(16) char xls[8 * 6144];   // [cg(8)][r(6)][w(64)]x16B = 48K
  __shared__ __align__(16) char wls[8 * 2048];   // [cg(8)][co(128)]x16B = 16K
  __shared__ float red[4][8][2];

  int blk = blockIdx.x;
  int rt = blk & 15, b = (blk >> 4) & 15, e = blk >> 8;
  int tid = threadIdx.x, lane = tid & 63, wave = tid >> 6;
  int quad = lane >> 4, l15 = lane & 15;
  int h0 = rt * 4;
  int h_local = wave;

  f32x4 acc[8][4];
#pragma unroll
  for (int mt = 0; mt < 8; ++mt)
#pragma unroll
    for (int nt = 0; nt < 4; ++nt) acc[mt][nt] = (f32x4){0.f, 0.f, 0.f, 0.f};

  bf16x8 bz;
#pragma unroll
  for (int j = 0; j < 8; ++j) bz[j] = (__bf16)0.f;

  for (int half = 0; half < 2; ++half) {
    __syncthreads();
#pragma unroll
    for (int s = 0; s < 12; ++s) {
      int seg = wave * 12 + s;
      int cg = seg / 6, r = seg % 6;
      int h = h0 - 1 + r;
      char* ldst = xls + cg * 6144 + r * 1024 + lane * 16;
      if ((unsigned)h < 64u) {
        const uint4* g = (const uint4*)((const char*)xT +
            ((size_t)((b * 64 + h) * 16) + half * 8 + cg) * 1024) + lane;
        *(uint4*)ldst = *g;
      } else {
        *(uint4*)ldst = make_uint4(0u, 0u, 0u, 0u);
      }
    }
    for (int tap = 0; tap < 9; ++tap) {
      int dr = tap / 3, ds = tap % 3;
      __syncthreads();
#pragma unroll
      for (int s = 0; s < 4; ++s) {
        int seg = wave * 4 + s;
        int cg = seg >> 1, cb = seg & 1;
        const uint4* g = (const uint4*)((const char*)wT +
            ((size_t)(((e * 9 + tap) * 16) + half * 8 + cg) * 128 + cb * 64) * 16) + lane;
        *(uint4*)(wls + cg * 2048 + cb * 1024 + lane * 16) = *g;
      }
      __syncthreads();
      int r_local = h_local + dr;
#pragma unroll
      for (int kc = 0; kc < 2; ++kc) {
        int cgq = kc * 4 + quad;
        bf16x8 af[8];
#pragma unroll
        for (int mt = 0; mt < 8; ++mt)
          af[mt] = *(const bf16x8*)(wls + cgq * 2048 + (mt * 16 + l15) * 16);
        bf16x8 bfr[4];
#pragma unroll
        for (int nt = 0; nt < 4; ++nt) {
          int w = nt * 16 + l15;
          int wsrc = w + ds - 1;
          bool valid = (unsigned)wsrc < 64u;
          int wc = valid ? wsrc : 0;
          bf16x8 v = *(const bf16x8*)(xls + cgq * 6144 + (r_local * 64 + wc) * 16);
          bfr[nt] = valid ? v : bz;
        }
#pragma unroll
        for (int mt = 0; mt < 8; ++mt)
#pragma unroll
          for (int nt = 0; nt < 4; ++nt)
            acc[mt][nt] = __builtin_amdgcn_mfma_f32_16x16x32_bf16(
                af[mt], bfr[nt], acc[mt][nt], 0, 0, 0);
      }
    }
  }

  int hh = h0 + h_local;
  bf16* yb = ys + (size_t)((e * 16 + b) * 128) * 4096;
#pragma unroll
  for (int mt = 0; mt < 8; ++mt) {
    float s = 0.f, ss = 0.f;
#pragma unroll
    for (int nt = 0; nt < 4; ++nt) {
      int w = nt * 16 + l15;
      int pos = hh * 64 + w;
#pragma unroll
      for (int r = 0; r < 4; ++r) {
        float v = acc[mt][nt][r];
        s += v;
        ss += v * v;
        int co = mt * 16 + quad * 4 + r;
        yb[(size_t)co * 4096 + pos] = f2bf(v);
      }
    }
#pragma unroll
    for (int off = 32; off; off >>= 1) {
      s += __shfl_down(s, off, 64);
      ss += __shfl_down(ss, off, 64);
    }
    if (lane == 0) { red[wave][mt][0] = s; red[wave][mt][1] = ss; }
  }
  __syncthreads();
  if (tid < 16) {
    int g = tid >> 1, which = tid & 1;
    float t = red[0][g][which] + red[1][g][which] + red[2][g][which] + red[3][g][which];
    atomicAdd(&statsE[((e * 16 + b) * 8 + g) * 2 + which], t);
  }
}

// ---------------- combine v2 (vectorized) -> bf16 channels-last ------------
// grid b x h = 1024 blocks. thread: w8 = t&7 (8 w-chunk), cog = t>>3 (4 co).
__global__ __launch_bounds__(256) void combine_cl(
    const float* __restrict__ x, const bf16* __restrict__ ys,
    const float* __restrict__ stE, const float* __restrict__ gns,
    const float* __restrict__ gnb, const float* __restrict__ wts,
    bf16* __restrict__ ccl) {
  __shared__ bf16 tile[64][132];
  int b = blockIdx.x >> 6, h = blockIdx.x & 63;
  int t = threadIdx.x;
  int w8 = t & 7, cog = t >> 3;
  int co0 = cog * 4;
  int g = co0 >> 4;
  int w0 = w8 * 8;
  int pid = (h >> 4) * 4 + (w0 >> 4);
  float wt_[8], m_[8], r_[8];
#pragma unroll
  for (int e = 0; e < 8; ++e) {
    float S = stE[((e * 16 + b) * 8 + g) * 2];
    float SS = stE[((e * 16 + b) * 8 + g) * 2 + 1];
    float mean = S * (1.f / 65536.f);
    float var = SS * (1.f / 65536.f) - mean * mean;
    m_[e] = mean;
    r_[e] = rsqrtf(var + 1e-5f);
    wt_[e] = wts[pid * 8 + e];
  }
  float acc[4][8];
#pragma unroll
  for (int c = 0; c < 4; ++c) {
    const float* xp = x + ((size_t)(b * 128 + co0 + c) << 12) + h * 64 + w0;
    float4 xa = *(const float4*)xp;
    float4 xb2 = *(const float4*)(xp + 4);
    acc[c][0] = xa.x; acc[c][1] = xa.y; acc[c][2] = xa.z; acc[c][3] = xa.w;
    acc[c][4] = xb2.x; acc[c][5] = xb2.y; acc[c][6] = xb2.z; acc[c][7] = xb2.w;
  }
#pragma unroll
  for (int e = 0; e < 8; ++e) {
#pragma unroll
    for (int c = 0; c < 4; ++c) {
      int co = co0 + c;
      float gscale = gns[e * 128 + co] * r_[e];
      float gshift = gnb[e * 128 + co] - m_[e] * gscale;
      uint4 raw = *(const uint4*)(ys + ((size_t)((e * 16 + b) * 128 + co) << 12) + h * 64 + w0);
      const bf16* pv = (const bf16*)&raw;
#pragma unroll
      for (int j = 0; j < 8; ++j) {
        float yn = bf2f(pv[j]) * gscale + gshift;
        acc[c][j] += siluf(yn) * wt_[e];
      }
    }
  }
#pragma unroll
  for (int j = 0; j < 8; ++j) {
    bf16 tmp[4];
#pragma unroll
    for (int c = 0; c < 4; ++c) tmp[c] = f2bf(acc[c][j]);
    *(uint2*)&tile[w0 + j][co0] = *(const uint2*)tmp;
  }
  __syncthreads();
  int row = t >> 2, q = t & 3;
  char* dst = (char*)ccl + ((size_t)(b * 4096 + h * 64 + row)) * 256 + q * 64;
  const char* src = (const char*)&tile[row][0] + q * 64;
#pragma unroll
  for (int i = 0; i < 4; ++i)
    *(uint4*)(dst + i * 16) = *(const uint4*)(src + i * 16);
}

// ---------------- pw1 MFMA: h1[hc=512][n=65536] = w[hc][ci] @ ccl[n][ci] ---
__global__ __launch_bounds__(256) void pw1_mfma(
    const bf16* __restrict__ ccl, const bf16* __restrict__ wp1T,
    bf16* __restrict__ h1cl, float* __restrict__ stats1) {
  __shared__ __align__(16) char ls[65536];
  __shared__ float red[4][2][2];
  char* als = ls;
  char* bls = ls + 32768;
  int blk = blockIdx.x;
  int ntile = blk & 511, mtile = blk >> 9;
  int n0 = ntile * 128, m0 = mtile * 128;
  int t = threadIdx.x, lane = t & 63, wave = t >> 6;
  int quad = lane >> 4, l15 = lane & 15;
  int b = n0 >> 12;

#pragma unroll
  for (int i = 0; i < 8; ++i) {
    int id = t + 256 * i;
    int r = id >> 4, c = id & 15;
    *(uint4*)(als + c * 2048 + r * 16) =
        *(const uint4*)((const char*)wp1T + (size_t)(m0 + r) * 256 + c * 16);
    *(uint4*)(bls + c * 2048 + r * 16) =
        *(const uint4*)((const char*)ccl + (size_t)(n0 + r) * 256 + c * 16);
  }
  __syncthreads();

  f32x4 acc[8][2];
#pragma unroll
  for (int mt = 0; mt < 8; ++mt)
#pragma unroll
    for (int nt = 0; nt < 2; ++nt) acc[mt][nt] = (f32x4){0.f, 0.f, 0.f, 0.f};

#pragma unroll
  for (int kc = 0; kc < 4; ++kc) {
    int cgq = kc * 4 + quad;
    bf16x8 af[8];
#pragma unroll
    for (int mt = 0; mt < 8; ++mt)
      af[mt] = *(const bf16x8*)(als + cgq * 2048 + (mt * 16 + l15) * 16);
    bf16x8 bfr[2];
#pragma unroll
    for (int nt = 0; nt < 2; ++nt)
      bfr[nt] = *(const bf16x8*)(bls + cgq * 2048 + (wave * 32 + nt * 16 + l15) * 16);
#pragma unroll
    for (int mt = 0; mt < 8; ++mt)
#pragma unroll
      for (int nt = 0; nt < 2; ++nt)
        acc[mt][nt] = __builtin_amdgcn_mfma_f32_16x16x32_bf16(
            af[mt], bfr[nt], acc[mt][nt], 0, 0, 0);
  }

  __syncthreads();
  float s[2] = {0.f, 0.f}, ss[2] = {0.f, 0.f};
  bf16* tile = (bf16*)ls;  // row stride 132 elems = 264 B
#pragma unroll
  for (int mt = 0; mt < 8; ++mt) {
    int gi = mt >> 2;
#pragma unroll
    for (int nt = 0; nt < 2; ++nt) {
      int n = wave * 32 + nt * 16 + l15;
#pragma unroll
      for (int r = 0; r < 4; ++r) {
        float v = acc[mt][nt][r];
        s[gi] += v;
        ss[gi] += v * v;
        tile[n * 132 + mt * 16 + quad * 4 + r] = f2bf(v);
      }
    }
  }
#pragma unroll
  for (int gi = 0; gi < 2; ++gi) {
#pragma unroll
    for (int off = 32; off; off >>= 1) {
      s[gi] += __shfl_down(s[gi], off, 64);
      ss[gi] += __shfl_down(ss[gi], off, 64);
    }
  }
  if (lane == 0) {
    red[wave][0][0] = s[0]; red[wave][0][1] = ss[0];
    red[wave][1][0] = s[1]; red[wave][1][1] = ss[1];
  }
  __syncthreads();
  if (t < 4) {
    int gi = t >> 1, which = t & 1;
    float v = red[0][gi][which] + red[1][gi][which] + red[2][gi][which] + red[3][gi][which];
    atomicAdd(&stats1[(b * 8 + mtile * 2 + gi) * 2 + which], v);
  }
#pragma unroll
  for (int i = 0; i < 8; ++i) {
    int id = t + 256 * i;
    int r = id >> 4, q = id & 15;
    char* dst = (char*)h1cl + (size_t)(n0 + r) * 1024 + m0 * 2 + q * 16;
    const char* src = (const char*)tile + r * 264 + q * 16;
    *(uint4*)dst = *(const uint4*)src;
  }
}

// ---------------- dw3x3: LDS-staged GN1+SiLU tile + sliding stencil --------
__global__ __launch_bounds__(256) void dw_cl(
    const bf16* __restrict__ h1cl, const float* __restrict__ w_dw,
    const float* __restrict__ st1, const float* __restrict__ gs,
    const float* __restrict__ gb, bf16* __restrict__ h2cl,
    float* __restrict__ stats2) {
  __shared__ __align__(16) bf16 tile[18 * 66 * 16];  // 38016 B
  __shared__ float red2[4][2];
  int blk = blockIdx.x;
  int ht = blk & 3, hcg = (blk >> 2) & 31, b = blk >> 7;
  int h0 = ht * 16;
  int hc0 = hcg * 16;
  int hcb = hcg >> 2;
  int t = threadIdx.x;

  float S1 = st1[(b * 8 + hcb) * 2], SS1 = st1[(b * 8 + hcb) * 2 + 1];
  float mean = S1 * (1.f / 262144.f);
  float rstd = rsqrtf(SS1 * (1.f / 262144.f) - mean * mean + 1e-5f);
  float scale[16], shift[16];
#pragma unroll
  for (int j = 0; j < 16; ++j) {
    float g = gs[hc0 + j];
    scale[j] = rstd * g;
    shift[j] = gb[hc0 + j] - mean * rstd * g;
  }

  for (int i = 0; i < 5; ++i) {
    int idx = t + 256 * i;
    if (idx >= 1188) break;
    int row = idx / 66, wslot = idx - row * 66;
    int hh = h0 - 1 + row;
    int w = wslot - 1;
    int swz = (wslot >> 2) & 3;
    bf16* dst = tile + (row * 66 + wslot) * 16;
    if ((unsigned)hh < 64u && (unsigned)w < 64u) {
      const char* p = (const char*)h1cl + ((size_t)(b * 4096 + hh * 64 + w) * 512 + hc0) * 2;
      uint4 a0 = *(const uint4*)p;
      uint4 a1 = *(const uint4*)(p + 16);
      const bf16* pv = (const bf16*)&a0;
      const bf16* pv1 = (const bf16*)&a1;
      bf16 outv[16];
#pragma unroll
      for (int j = 0; j < 8; ++j)
        outv[j] = f2bf(siluf(bf2f(pv[j]) * scale[j] + shift[j]));
#pragma unroll
      for (int j = 0; j < 8; ++j)
        outv[8 + j] = f2bf(siluf(bf2f(pv1[j]) * scale[8 + j] + shift[8 + j]));
#pragma unroll
      for (int qq = 0; qq < 4; ++qq) {
        int ph = (qq + swz) & 3;
        *(uint2*)(dst + ph * 4) = *(const uint2*)(outv + qq * 4);
      }
    } else {
      *(uint4*)dst = make_uint4(0u, 0u, 0u, 0u);
      *(uint4*)(dst + 8) = make_uint4(0u, 0u, 0u, 0u);
    }
  }
  __syncthreads();

  int w = t & 63, q = t >> 6;
  float wv[9][4];
#pragma unroll
  for (int j = 0; j < 4; ++j) {
    int hc = hc0 + q * 4 + j;
#pragma unroll
    for (int tap = 0; tap < 9; ++tap) wv[tap][j] = w_dw[hc * 9 + tap];
  }

  f32x4 win[3][3];
  float acc_s = 0.f, acc_ss = 0.f;

  auto ld4 = [&](int r, int dwi) -> f32x4 {
    int slot = w + dwi;
    int ph = (q + (slot >> 2)) & 3;
    const bf16* p = tile + (r * 66 + slot) * 16 + ph * 4;
    uint2 u = *(const uint2*)p;
    const bf16* pb = (const bf16*)&u;
    return (f32x4){bf2f(pb[0]), bf2f(pb[1]), bf2f(pb[2]), bf2f(pb[3])};
  };

#pragma unroll
  for (int dwi = 0; dwi < 3; ++dwi) {
    win[0][dwi] = ld4(0, dwi);
    win[1][dwi] = ld4(1, dwi);
  }
#pragma unroll
  for (int orow = 0; orow < 16; ++orow) {
    int rnew = orow + 2;
    int ringn = rnew % 3;
#pragma unroll
    for (int dwi = 0; dwi < 3; ++dwi) win[ringn][dwi] = ld4(rnew, dwi);
    f32x4 acc = (f32x4){0.f, 0.f, 0.f, 0.f};
#pragma unroll
    for (int dr = 0; dr < 3; ++dr) {
      int ring = (orow + dr) % 3;
#pragma unroll
      for (int dwi = 0; dwi < 3; ++dwi) {
#pragma unroll
        for (int j = 0; j < 4; ++j)
          acc[j] = fmaf(win[ring][dwi][j], wv[dr * 3 + dwi][j], acc[j]);
      }
    }
#pragma unroll
    for (int j = 0; j < 4; ++j) { acc_s += acc[j]; acc_ss += acc[j] * acc[j]; }
    if (!(orow & 1) && !(w & 1)) {
      int hglob = h0 + orow;
      int pos2 = (hglob >> 1) * 32 + (w >> 1);
      bf16 tmp[4];
#pragma unroll
      for (int j = 0; j < 4; ++j) tmp[j] = f2bf(acc[j]);
      *(uint2*)((char*)h2cl + ((size_t)(b * 1024 + pos2) * 512 + hc0 + q * 4) * 2) =
          *(const uint2*)tmp;
    }
  }

#pragma unroll
  for (int off = 32; off; off >>= 1) {
    acc_s += __shfl_down(acc_s, off, 64);
    acc_ss += __shfl_down(acc_ss, off, 64);
  }
  int wave = t >> 6;
  if ((t & 63) == 0) { red2[wave][0] = acc_s; red2[wave][1] = acc_ss; }
  __syncthreads();
  if (t < 2) {
    float v = red2[0][t] + red2[1][t] + red2[2][t] + red2[3][t];
    atomicAdd(&stats2[(b * 8 + hcb) * 2 + t], v);
  }
}

// ---------------- pw2 MFMA with fused GN2+SiLU on B staging ----------------
__global__ __launch_bounds__(256) void pw2_mfma(
    const bf16* __restrict__ h2raw, const bf16* __restrict__ wp2T,
    const float* __restrict__ st2, const float* __restrict__ gs2,
    const float* __restrict__ gb2, float* __restrict__ h3,
    float* __restrict__ stats3) {
  __shared__ __align__(16) char als[2][8192];
  __shared__ __align__(16) char bls[2][4096];
  __shared__ float red[4][8][2];
  int blk = blockIdx.x;
  int n0 = blk * 64;
  int b = n0 >> 10, posb = n0 & 1023;
  int t = threadIdx.x, lane = t & 63, wave = t >> 6;
  int quad = lane >> 4, l15 = lane & 15;
  int wbase = wave * 16;

  f32x4 acc[8];
#pragma unroll
  for (int mt = 0; mt < 8; ++mt) acc[mt] = (f32x4){0.f, 0.f, 0.f, 0.f};

  auto stageB = [&](int buf, int kc) {
    int c4 = t >> 6, r = t & 63;
    int hcb = (kc * 4 + c4) * 8;
    int g = hcb >> 6;
    float S2 = st2[(b * 8 + g) * 2], SS2 = st2[(b * 8 + g) * 2 + 1];
    float mean = S2 * (1.f / 262144.f);
    float rstd = rsqrtf(SS2 * (1.f / 262144.f) - mean * mean + 1e-5f);
    uint4 raw = *(const uint4*)((const char*)h2raw + (size_t)(n0 + r) * 1024 + (kc * 4 + c4) * 16);
    const bf16* pv = (const bf16*)&raw;
    bf16 outv[8];
#pragma unroll
    for (int j = 0; j < 8; ++j) {
      float v = bf2f(pv[j]);
      v = (v - mean) * rstd * gs2[hcb + j] + gb2[hcb + j];
      outv[j] = f2bf(siluf(v));
    }
    *(uint4*)(bls[buf] + c4 * 1024 + r * 16) = *(const uint4*)outv;
  };

  {
#pragma unroll
    for (int i = 0; i < 2; ++i) {
      int id = t + 256 * i;
      int c4 = id >> 7, r = id & 127;
      *(uint4*)(als[0] + c4 * 2048 + r * 16) =
          *(const uint4*)((const char*)wp2T + (size_t)r * 1024 + c4 * 16);
    }
    stageB(0, 0);
  }
  for (int kc = 0; kc < 16; ++kc) {
    __syncthreads();
    if (kc + 1 < 16) {
      int nb = (kc + 1) & 1;
#pragma unroll
      for (int i = 0; i < 2; ++i) {
        int id = t + 256 * i;
        int c4 = id >> 7, r = id & 127;
        *(uint4*)(als[nb] + c4 * 2048 + r * 16) =
            *(const uint4*)((const char*)wp2T + (size_t)r * 1024 + ((kc + 1) * 4 + c4) * 16);
      }
      stageB(nb, kc + 1);
    }
    int buf = kc & 1;
    bf16x8 bf1 = *(const bf16x8*)(bls[buf] + quad * 1024 + (wbase + l15) * 16);
#pragma unroll
    for (int mt = 0; mt < 8; ++mt) {
      bf16x8 af = *(const bf16x8*)(als[buf] + quad * 2048 + (mt * 16 + l15) * 16);
      acc[mt] = __builtin_amdgcn_mfma_f32_16x16x32_bf16(af, bf1, acc[mt], 0, 0, 0);
    }
  }

#pragma unroll
  for (int mt = 0; mt < 8; ++mt) {
    float s = 0.f, ss = 0.f;
    int pos = posb + wbase + l15;
#pragma unroll
    for (int r = 0; r < 4; ++r) {
      float v = acc[mt][r];
      s += v;
      ss += v * v;
      int co = mt * 16 + quad * 4 + r;
      h3[(size_t)(b * 128 + co) * 1024 + pos] = v;
    }
#pragma unroll
    for (int off = 32; off; off >>= 1) {
      s += __shfl_down(s, off, 64);
      ss += __shfl_down(ss, off, 64);
    }
    if (lane == 0) { red[wave][mt][0] = s; red[wave][mt][1] = ss; }
  }
  __syncthreads();
  if (t < 16) {
    int mt = t >> 1, which = t & 1;
    float v = red[0][mt][which] + red[1][mt][which] + red[2][mt][which] + red[3][mt][which];
    atomicAdd(&stats3[(b * 8 + mt) * 2 + which], v);
  }
}

// ---------------- final GN+SiLU -> d_out (fp32) ----------------------------
__global__ void out_kernel(const float* __restrict__ h3, const float* __restrict__ stats,
                           const float* __restrict__ gs, const float* __restrict__ gb,
                           float* __restrict__ out) {
  const int total = B_ * COUT_ * 1024;
  for (int idx = blockIdx.x * blockDim.x + threadIdx.x; idx < total; idx += gridDim.x * blockDim.x) {
    int c = (idx >> 10) & 127;
    int b = idx >> 17;
    int bg = b * 8 + (c >> 4);
    float S = stats[bg * 2], SS = stats[bg * 2 + 1];
    float mean = S * (1.f / 16384.f);
    float var = SS * (1.f / 16384.f) - mean * mean;
    float rstd = rsqrtf(var + 1e-5f);
    float v = (h3[idx] - mean) * rstd * gs[c] + gb[c];
    out[idx] = siluf(v);
  }
}

extern "C" void kernel_launch(void* const* d_in, const int* in_sizes, int n_in,
                              void* d_out, int out_size, void* d_ws, size_t ws_size,
                              hipStream_t stream) {
  const float* x = (const float*)d_in[0];
  const float* w_exp = (const float*)d_in[1];
  const float* gn_exp_s = (const float*)d_in[2];
  const float* gn_exp_b = (const float*)d_in[3];
  const float* w1 = (const float*)d_in[4];
  const float* b1 = (const float*)d_in[5];
  const float* w2 = (const float*)d_in[6];
  const float* b2 = (const float*)d_in[7];
  const float* w_pw1 = (const float*)d_in[8];
  const float* gn1_s = (const float*)d_in[9];
  const float* gn1_b = (const float*)d_in[10];
  const float* w_dw = (const float*)d_in[11];
  const float* gn2_s = (const float*)d_in[12];
  const float* gn2_b = (const float*)d_in[13];
  const float* w_pw2 = (const float*)d_in[14];
  const float* gn3_s = (const float*)d_in[15];
  const float* gn3_b = (const float*)d_in[16];

  char* ws = (char*)d_ws;
  const size_t WP1T_OFF = 16384;
  const size_t WP2T_OFF = WP1T_OFF + 131072;
  const size_t XT_OFF = WP2T_OFF + 131072;                 // 278528
  const size_t WT_OFF = XT_OFF + 16777216;                 // 17055744
  const size_t YS_OFF = WT_OFF + 2359296;                  // 19415040
  const size_t NEEDED = YS_OFF + 134217728;                // 153632768
  if (ws_size < NEEDED) return;

  float* wts = (float*)ws;
  float* stats1 = (float*)(ws + 1024);
  float* stats2 = (float*)(ws + 2048);
  float* stats3 = (float*)(ws + 3072);
  float* statsE = (float*)(ws + 4096);
  bf16* wp1T = (bf16*)(ws + WP1T_OFF);
  bf16* wp2T = (bf16*)(ws + WP2T_OFF);
  bf16* xT = (bf16*)(ws + XT_OFF);
  bf16* ccl = (bf16*)(ws + XT_OFF);
  bf16* wT = (bf16*)(ws + WT_OFF);
  bf16* ys = (bf16*)(ws + YS_OFF);
  bf16* h1cl = (bf16*)(ws + YS_OFF);
  bf16* h2cl = (bf16*)(ws + YS_OFF + 67108864);
  float* h3 = (float*)(ws + YS_OFF + 83886080);

  prep_kernel<<<6145, 256, 0, stream>>>(x, w1, b1, w2, b2, w_exp, w_pw1, w_pw2,
                                        xT, wts, ws, wp1T, wp2T, wT);
  conv_mfma<<<E_ * B_ * 16, 256, 0, stream>>>(xT, wT, statsE, ys);
  combine_cl<<<B_ * 64, 256, 0, stream>>>(x, ys, statsE, gn_exp_s, gn_exp_b, wts, ccl);
  pw1_mfma<<<4 * 512, 256, 0, stream>>>(ccl, wp1T, h1cl, stats1);
  dw_cl<<<B_ * 32 * 4, 256, 0, stream>>>(h1cl, w_dw, stats1, gn1_s, gn1_b, h2cl, stats2);
  pw2_mfma<<<256, 256, 0, stream>>>(h2cl, wp2T, stats2, gn2_s, gn2_b, h3, stats3);
  out_kernel<<<1024, 256, 0, stream>>>(h3, stats3, gn3_s, gn3_b, (float*)d_out);
}